// Round 15
// baseline (928.940 us; speedup 1.0000x reference)
//
#include <hip/hip_runtime.h>
#include <hip/hip_bf16.h>

#define FIN   128
#define HEADS 4
#define HID   32
#define NCLS  40
#define NEG_SLOPE 0.2f

#define BKT_SH 10
#define BKT    1024
#define NB_MAX 128
#define TILE_E 8192
#define CAP_SH 14
#define CAP    16384        // per-bucket pairs/cols capacity (mean 13.6K + 24 sigma)

typedef __bf16 bf16x8 __attribute__((ext_vector_type(8)));
typedef float  f32x4  __attribute__((ext_vector_type(4)));

__device__ inline unsigned short bf16_rne(float f) {
    unsigned u = __float_as_uint(f);
    return (unsigned short)((u + 0x7fffu + ((u >> 16) & 1u)) >> 16);
}
__device__ inline float bf16_to_f(unsigned short h) {
    return __uint_as_float(((unsigned)h) << 16);
}

// ===== packing device helpers ===============================================
__device__ inline void packW_dev(const float* __restrict__ W, unsigned short* __restrict__ Bhi,
                                 unsigned short* __restrict__ Blo, int NO, int NC, int idx) {
    int i = idx & 7;
    int rest = idx >> 3;
    int l = rest & 63;
    int rest2 = rest >> 6;
    int c = rest2 % NC;
    int t = rest2 / NC;
    int k   = t * 32 + (l >> 4) * 8 + i;
    int col = c * 16 + (l & 15);
    float val = (col < NO) ? W[(size_t)k * NO + col] : 0.f;
    unsigned short hi = bf16_rne(val);
    unsigned short lo = bf16_rne(val - bf16_to_f(hi));
    Bhi[idx] = hi;
    Blo[idx] = lo;
}

__device__ inline void packS_dev(const float* __restrict__ W, const float* __restrict__ asrc,
                                 const float* __restrict__ adst, unsigned short* __restrict__ Shi,
                                 unsigned short* __restrict__ Slo, int NO, int HH, int CH, int idx) {
    int i = idx & 7;
    int l = (idx >> 3) & 63;
    int t = idx >> 9;
    int k = t * 32 + (l >> 4) * 8 + i;
    int j = l & 15;
    float val = 0.f;
    if (j < 2 * HH) {
        int h = (j < HH) ? j : j - HH;
        const float* av = (j < HH) ? (asrc + h * CH) : (adst + h * CH);
        const float* wr = W + (size_t)k * NO + h * CH;
        for (int c = 0; c < CH; ++c) val += wr[c] * av[c];
    }
    unsigned short hi = bf16_rne(val);
    unsigned short lo = bf16_rne(val - bf16_to_f(hi));
    Shi[idx] = hi;
    Slo[idx] = lo;
}

// all W/S packing + gcur1 init (bucket bases) + degcnt zeroing
__global__ __launch_bounds__(256) void packAll_k(
        const float* __restrict__ W0, const float* __restrict__ W1, const float* __restrict__ W2,
        const float* __restrict__ as0, const float* __restrict__ ad0,
        const float* __restrict__ as1, const float* __restrict__ ad1,
        const float* __restrict__ as2, const float* __restrict__ ad2,
        unsigned short* __restrict__ Bhi0, unsigned short* __restrict__ Blo0,
        unsigned short* __restrict__ Bhi1, unsigned short* __restrict__ Blo1,
        unsigned short* __restrict__ Bhi2, unsigned short* __restrict__ Blo2,
        unsigned short* __restrict__ Shi0, unsigned short* __restrict__ Slo0,
        unsigned short* __restrict__ Shi1, unsigned short* __restrict__ Slo1,
        unsigned short* __restrict__ Shi2, unsigned short* __restrict__ Slo2,
        int* __restrict__ gcur1, int* __restrict__ degcnt) {
    int gid = blockIdx.x * 256 + threadIdx.x;
    if      (gid < 16384) packW_dev(W0, Bhi0, Blo0, 128, 8, gid);
    else if (gid < 32768) packW_dev(W1, Bhi1, Blo1, 128, 8, gid - 16384);
    else if (gid < 38912) packW_dev(W2, Bhi2, Blo2, NCLS, 3, gid - 32768);
    else if (gid < 40960) packS_dev(W0, as0, ad0, Shi0, Slo0, 128, 4, HID, gid - 38912);
    else if (gid < 43008) packS_dev(W1, as1, ad1, Shi1, Slo1, 128, 4, HID, gid - 40960);
    else if (gid < 45056) packS_dev(W2, as2, ad2, Shi2, Slo2, NCLS, 1, NCLS, gid - 43008);
    else if (gid < 45056 + NB_MAX) gcur1[gid - 45056] = (gid - 45056) << CAP_SH;
    else if (gid < 45056 + NB_MAX + 256) degcnt[gid - 45056 - NB_MAX] = 0;
}

// ===== layer-0 fused GEMM + scores (fp32 X, split-A) ========================
template<int NC, int HH>
__global__ __launch_bounds__(256) void gemm_fused_k(
        const float* __restrict__ X, const unsigned short* __restrict__ Bhi,
        const unsigned short* __restrict__ Blo, const unsigned short* __restrict__ Shi,
        const unsigned short* __restrict__ Slo, unsigned short* __restrict__ Hbf,
        float* __restrict__ ssrc, float* __restrict__ sdst, int n, int NO) {
    int wave = threadIdx.x >> 6;
    int lane = threadIdx.x & 63;
    int rowbase = (blockIdx.x * 4 + wave) * 32;
    if (rowbase >= n) return;
    int r0 = lane & 15, kg = lane >> 4;

    f32x4 acc[2][NC];
    f32x4 accS[2];
#pragma unroll
    for (int rt = 0; rt < 2; ++rt) {
        accS[rt] = f32x4{0.f, 0.f, 0.f, 0.f};
#pragma unroll
        for (int c = 0; c < NC; ++c) acc[rt][c] = f32x4{0.f, 0.f, 0.f, 0.f};
    }

    for (int t = 0; t < 4; ++t) {
        union U { unsigned short u[8]; bf16x8 v; };
        U ah[2], al[2];
#pragma unroll
        for (int rt = 0; rt < 2; ++rt) {
            int row = min(rowbase + rt * 16 + r0, n - 1);
            const float* xp = X + (size_t)row * 128 + t * 32 + kg * 8;
            float4 xa = *reinterpret_cast<const float4*>(xp);
            float4 xb = *reinterpret_cast<const float4*>(xp + 4);
            float f[8] = {xa.x, xa.y, xa.z, xa.w, xb.x, xb.y, xb.z, xb.w};
#pragma unroll
            for (int i = 0; i < 8; ++i) {
                unsigned short h = bf16_rne(f[i]);
                ah[rt].u[i] = h;
                al[rt].u[i] = bf16_rne(f[i] - bf16_to_f(h));
            }
        }
#pragma unroll
        for (int c = 0; c < NC; ++c) {
            size_t boff = (((size_t)t * NC + c) * 64 + lane) * 8;
            bf16x8 bh = *reinterpret_cast<const bf16x8*>(Bhi + boff);
            bf16x8 bl = *reinterpret_cast<const bf16x8*>(Blo + boff);
#pragma unroll
            for (int rt = 0; rt < 2; ++rt) {
                acc[rt][c] = __builtin_amdgcn_mfma_f32_16x16x32_bf16(ah[rt].v, bh, acc[rt][c], 0, 0, 0);
                acc[rt][c] = __builtin_amdgcn_mfma_f32_16x16x32_bf16(al[rt].v, bh, acc[rt][c], 0, 0, 0);
                acc[rt][c] = __builtin_amdgcn_mfma_f32_16x16x32_bf16(ah[rt].v, bl, acc[rt][c], 0, 0, 0);
            }
        }
        {
            size_t soff = ((size_t)t * 64 + lane) * 8;
            bf16x8 sh = *reinterpret_cast<const bf16x8*>(Shi + soff);
            bf16x8 sl = *reinterpret_cast<const bf16x8*>(Slo + soff);
#pragma unroll
            for (int rt = 0; rt < 2; ++rt) {
                accS[rt] = __builtin_amdgcn_mfma_f32_16x16x32_bf16(ah[rt].v, sh, accS[rt], 0, 0, 0);
                accS[rt] = __builtin_amdgcn_mfma_f32_16x16x32_bf16(al[rt].v, sh, accS[rt], 0, 0, 0);
                accS[rt] = __builtin_amdgcn_mfma_f32_16x16x32_bf16(ah[rt].v, sl, accS[rt], 0, 0, 0);
            }
        }
    }

#pragma unroll
    for (int rt = 0; rt < 2; ++rt)
#pragma unroll
        for (int r = 0; r < 4; ++r) {
            int row = rowbase + rt * 16 + kg * 4 + r;
            if (row >= n) continue;
            if (HH == 4) {
                if (r0 < 4)      ssrc[(size_t)row * 4 + r0]       = accS[rt][r];
                else if (r0 < 8) sdst[(size_t)row * 4 + (r0 - 4)] = accS[rt][r];
            } else {
                if (r0 == 0)      ssrc[row] = accS[rt][r];
                else if (r0 == 1) sdst[row] = accS[rt][r];
            }
#pragma unroll
            for (int c = 0; c < NC; ++c) {
                int col = c * 16 + r0;
                if (col < NO)
                    Hbf[(size_t)row * NO + col] = bf16_rne(acc[rt][c][r]);
            }
        }
}

// ===== layers 1/2 GEMM: bf16 A + scores via MFMA; optional split-40 out =====
template<int NC, int HH, bool SPLIT>
__global__ __launch_bounds__(256) void gemm_bf16s_k(
        const unsigned short* __restrict__ Xbf, const unsigned short* __restrict__ Bhi,
        const unsigned short* __restrict__ Blo, const unsigned short* __restrict__ Shi,
        const unsigned short* __restrict__ Slo, unsigned short* __restrict__ Hbf,
        unsigned short* __restrict__ H8,
        float* __restrict__ ssrc, float* __restrict__ sdst, int n, int NO) {
    int wave = threadIdx.x >> 6;
    int lane = threadIdx.x & 63;
    int rowbase = (blockIdx.x * 4 + wave) * 32;
    if (rowbase >= n) return;
    int r0 = lane & 15, kg = lane >> 4;

    f32x4 acc[2][NC];
    f32x4 accS[2];
#pragma unroll
    for (int rt = 0; rt < 2; ++rt) {
        accS[rt] = f32x4{0.f, 0.f, 0.f, 0.f};
#pragma unroll
        for (int c = 0; c < NC; ++c) acc[rt][c] = f32x4{0.f, 0.f, 0.f, 0.f};
    }

    for (int t = 0; t < 4; ++t) {
        bf16x8 av[2];
#pragma unroll
        for (int rt = 0; rt < 2; ++rt) {
            int row = min(rowbase + rt * 16 + r0, n - 1);
            av[rt] = *reinterpret_cast<const bf16x8*>(Xbf + (size_t)row * 128 + t * 32 + kg * 8);
        }
#pragma unroll
        for (int c = 0; c < NC; ++c) {
            size_t boff = (((size_t)t * NC + c) * 64 + lane) * 8;
            bf16x8 bh = *reinterpret_cast<const bf16x8*>(Bhi + boff);
            bf16x8 bl = *reinterpret_cast<const bf16x8*>(Blo + boff);
#pragma unroll
            for (int rt = 0; rt < 2; ++rt) {
                acc[rt][c] = __builtin_amdgcn_mfma_f32_16x16x32_bf16(av[rt], bh, acc[rt][c], 0, 0, 0);
                acc[rt][c] = __builtin_amdgcn_mfma_f32_16x16x32_bf16(av[rt], bl, acc[rt][c], 0, 0, 0);
            }
        }
        {
            size_t soff = ((size_t)t * 64 + lane) * 8;
            bf16x8 sh = *reinterpret_cast<const bf16x8*>(Shi + soff);
            bf16x8 sl = *reinterpret_cast<const bf16x8*>(Slo + soff);
#pragma unroll
            for (int rt = 0; rt < 2; ++rt) {
                accS[rt] = __builtin_amdgcn_mfma_f32_16x16x32_bf16(av[rt], sh, accS[rt], 0, 0, 0);
                accS[rt] = __builtin_amdgcn_mfma_f32_16x16x32_bf16(av[rt], sl, accS[rt], 0, 0, 0);
            }
        }
    }

#pragma unroll
    for (int rt = 0; rt < 2; ++rt)
#pragma unroll
        for (int r = 0; r < 4; ++r) {
            int row = rowbase + rt * 16 + kg * 4 + r;
            if (row >= n) continue;
            if (HH == 4) {
                if (r0 < 4)      ssrc[(size_t)row * 4 + r0]       = accS[rt][r];
                else if (r0 < 8) sdst[(size_t)row * 4 + (r0 - 4)] = accS[rt][r];
            } else {
                if (r0 == 0)      ssrc[row] = accS[rt][r];
                else if (r0 == 1) sdst[row] = accS[rt][r];
            }
#pragma unroll
            for (int c = 0; c < NC; ++c) {
                int col = c * 16 + r0;
                if (col < NO) {
                    unsigned short b = bf16_rne(acc[rt][c][r]);
                    if (!SPLIT) {
                        Hbf[(size_t)row * 128 + col] = b;
                    } else {
                        if (col < 32) Hbf[(size_t)row * 32 + col] = b;
                        else          H8[(size_t)row * 8 + (col - 32)] = b;
                    }
                }
            }
        }
}

// ===== CSR build: one-pass bucket partition (fixed CAP), beg/end rows =======
__global__ __launch_bounds__(256) void placeA_k(const int* __restrict__ ei, int E, int Etot,
                                                int nb, int* __restrict__ gcur1,
                                                unsigned* __restrict__ pairs) {
    __shared__ int h[NB_MAX];
    __shared__ int cur[NB_MAX];
    for (int i = threadIdx.x; i < nb; i += 256) h[i] = 0;
    __syncthreads();
    int base = blockIdx.x * TILE_E;
    int lim = min(base + TILE_E, Etot);
    for (int e = base + threadIdx.x; e < lim; e += 256) {
        int d = (e < E) ? ei[E + e] : e - E;
        atomicAdd(&h[d >> BKT_SH], 1);
    }
    __syncthreads();
    for (int i = threadIdx.x; i < nb; i += 256)
        cur[i] = h[i] ? atomicAdd(&gcur1[i], h[i]) : 0;
    __syncthreads();
    for (int e = base + threadIdx.x; e < lim; e += 256) {
        int s, d;
        if (e < E) { s = ei[e]; d = ei[E + e]; } else { s = d = e - E; }
        int b = d >> BKT_SH;
        int p = atomicAdd(&cur[b], 1);
        if (p < ((b + 1) << CAP_SH))
            pairs[p] = ((unsigned)s << BKT_SH) | (unsigned)(d & (BKT - 1));
    }
}

__global__ __launch_bounds__(256) void buildcsr_k(const unsigned* __restrict__ pairs,
                                                  const int* __restrict__ gcur1,
                                                  int* __restrict__ begA, int* __restrict__ endA,
                                                  int* __restrict__ cols, int* __restrict__ degcnt,
                                                  int n) {
    __shared__ int cnt[BKT];
    __shared__ int part[256];
    int b = blockIdx.x;
    int base = b << CAP_SH;
    int d0 = b << BKT_SH;
    int nd = min(BKT, n - d0);
    int total = min(gcur1[b] - base, CAP);
    for (int i = threadIdx.x; i < nd; i += 256) cnt[i] = 0;
    __syncthreads();
    for (int i = base + threadIdx.x; i < base + total; i += 256)
        atomicAdd(&cnt[pairs[i] & (BKT - 1)], 1);
    __syncthreads();

    int t = threadIdx.x;
    int i4 = t * 4;
    int myv[4];
    int s0 = 0;
#pragma unroll
    for (int j = 0; j < 4; ++j) { myv[j] = (i4 + j < nd) ? cnt[i4 + j] : 0; s0 += myv[j]; }
    part[t] = s0;
    __syncthreads();
    for (int off = 1; off < 256; off <<= 1) {
        int tv = (t >= off) ? part[t - off] : 0;
        __syncthreads();
        part[t] += tv;
        __syncthreads();
    }
    int run = base + part[t] - s0;
#pragma unroll
    for (int j = 0; j < 4; ++j) {
        if (i4 + j < nd) {
            begA[d0 + i4 + j] = run;
            endA[d0 + i4 + j] = run + myv[j];
            atomicAdd(&degcnt[min(myv[j], 255)], 1);
            cnt[i4 + j] = run;
            run += myv[j];
        }
    }
    __syncthreads();
    for (int i = base + threadIdx.x; i < base + total; i += 256) {
        unsigned p = pairs[i];
        int pos = atomicAdd(&cnt[p & (BKT - 1)], 1);
        cols[pos] = (int)(p >> BKT_SH);
    }
}

// exclusive scan of 256 degree-class counts -> class cursors
__global__ void scanDeg_k(const int* __restrict__ degcnt, int* __restrict__ degcur) {
    __shared__ int tmp[256];
    int l = threadIdx.x;
    int v = degcnt[l];
    tmp[l] = v;
    __syncthreads();
    for (int off = 1; off < 256; off <<= 1) {
        int t = (l >= off) ? tmp[l - off] : 0;
        __syncthreads();
        tmp[l] += t;
        __syncthreads();
    }
    degcur[l] = tmp[l] - v;
}

// scatter nodes into degree-sorted processing order
__global__ __launch_bounds__(256) void permScatter_k(const int* __restrict__ begA,
                                                     const int* __restrict__ endA,
                                                     int* __restrict__ degcur,
                                                     int* __restrict__ perm, int n) {
    int d = blockIdx.x * 256 + threadIdx.x;
    if (d >= n) return;
    int deg = endA[d] - begA[d];
    int pos = atomicAdd(&degcur[min(deg, 255)], 1);
    perm[pos] = d;
}

// ===== layers 0/1: single-pass unnormalized softmax + bf16 aggr (perm'd) ====
__global__ __launch_bounds__(256) void gat128_k(
        const int* __restrict__ perm, const int* __restrict__ begA, const int* __restrict__ endA,
        const int* __restrict__ cols, const unsigned short* __restrict__ Hbf,
        const float* __restrict__ ssrc, const float* __restrict__ sdst,
        const float* __restrict__ bias, unsigned short* __restrict__ outbf, int n) {
    int g = (blockIdx.x * 256 + threadIdx.x) >> 4;
    if (g >= n) return;
    int d = perm[g];
    int l = threadIdx.x & 15;
    int head = l >> 2;
    int beg = begA[d], end = endA[d];

    float sdh = sdst[(size_t)d * 4 + head];

    float4 a0 = {0.f, 0.f, 0.f, 0.f}, a1 = {0.f, 0.f, 0.f, 0.f};
    float4 c0 = {0.f, 0.f, 0.f, 0.f}, c1 = {0.f, 0.f, 0.f, 0.f};
    float den = 0.f;

    auto proc = [&](int i, float4& p0, float4& p1) {
        int s = cols[i];
        float v = ssrc[(size_t)s * 4 + head] + sdh;
        v = (v >= 0.f) ? v : NEG_SLOPE * v;
        float a = __expf(v);
        den += a;
        const unsigned short* hp = Hbf + (size_t)s * 128 + l * 8;
        uint4 q = *reinterpret_cast<const uint4*>(hp);
        p0.x += a * __uint_as_float(q.x << 16);
        p0.y += a * __uint_as_float(q.x & 0xffff0000u);
        p0.z += a * __uint_as_float(q.y << 16);
        p0.w += a * __uint_as_float(q.y & 0xffff0000u);
        p1.x += a * __uint_as_float(q.z << 16);
        p1.y += a * __uint_as_float(q.z & 0xffff0000u);
        p1.z += a * __uint_as_float(q.w << 16);
        p1.w += a * __uint_as_float(q.w & 0xffff0000u);
    };

    int i = beg;
    int rem = (end - beg) & 3;
    if (rem & 1) { proc(i, a0, a1); ++i; }
    if (rem & 2) { proc(i, a0, a1); proc(i + 1, c0, c1); i += 2; }
    for (; i < end; i += 4) {
        int s0 = cols[i], s1 = cols[i + 1], s2 = cols[i + 2], s3 = cols[i + 3];
        float w0 = ssrc[(size_t)s0 * 4 + head] + sdh;
        float w1 = ssrc[(size_t)s1 * 4 + head] + sdh;
        float w2 = ssrc[(size_t)s2 * 4 + head] + sdh;
        float w3 = ssrc[(size_t)s3 * 4 + head] + sdh;
        uint4 q0 = *reinterpret_cast<const uint4*>(Hbf + (size_t)s0 * 128 + l * 8);
        uint4 q1 = *reinterpret_cast<const uint4*>(Hbf + (size_t)s1 * 128 + l * 8);
        uint4 q2 = *reinterpret_cast<const uint4*>(Hbf + (size_t)s2 * 128 + l * 8);
        uint4 q3 = *reinterpret_cast<const uint4*>(Hbf + (size_t)s3 * 128 + l * 8);
        w0 = (w0 >= 0.f) ? w0 : NEG_SLOPE * w0;
        w1 = (w1 >= 0.f) ? w1 : NEG_SLOPE * w1;
        w2 = (w2 >= 0.f) ? w2 : NEG_SLOPE * w2;
        w3 = (w3 >= 0.f) ? w3 : NEG_SLOPE * w3;
        float e0 = __expf(w0), e1 = __expf(w1);
        float e2 = __expf(w2), e3 = __expf(w3);
        den += e0 + e1 + e2 + e3;
        a0.x += e0 * __uint_as_float(q0.x << 16);
        a0.y += e0 * __uint_as_float(q0.x & 0xffff0000u);
        a0.z += e0 * __uint_as_float(q0.y << 16);
        a0.w += e0 * __uint_as_float(q0.y & 0xffff0000u);
        a1.x += e0 * __uint_as_float(q0.z << 16);
        a1.y += e0 * __uint_as_float(q0.z & 0xffff0000u);
        a1.z += e0 * __uint_as_float(q0.w << 16);
        a1.w += e0 * __uint_as_float(q0.w & 0xffff0000u);
        c0.x += e1 * __uint_as_float(q1.x << 16);
        c0.y += e1 * __uint_as_float(q1.x & 0xffff0000u);
        c0.z += e1 * __uint_as_float(q1.y << 16);
        c0.w += e1 * __uint_as_float(q1.y & 0xffff0000u);
        c1.x += e1 * __uint_as_float(q1.z << 16);
        c1.y += e1 * __uint_as_float(q1.z & 0xffff0000u);
        c1.z += e1 * __uint_as_float(q1.w << 16);
        c1.w += e1 * __uint_as_float(q1.w & 0xffff0000u);
        a0.x += e2 * __uint_as_float(q2.x << 16);
        a0.y += e2 * __uint_as_float(q2.x & 0xffff0000u);
        a0.z += e2 * __uint_as_float(q2.y << 16);
        a0.w += e2 * __uint_as_float(q2.y & 0xffff0000u);
        a1.x += e2 * __uint_as_float(q2.z << 16);
        a1.y += e2 * __uint_as_float(q2.z & 0xffff0000u);
        a1.z += e2 * __uint_as_float(q2.w << 16);
        a1.w += e2 * __uint_as_float(q2.w & 0xffff0000u);
        c0.x += e3 * __uint_as_float(q3.x << 16);
        c0.y += e3 * __uint_as_float(q3.x & 0xffff0000u);
        c0.z += e3 * __uint_as_float(q3.y << 16);
        c0.w += e3 * __uint_as_float(q3.y & 0xffff0000u);
        c1.x += e3 * __uint_as_float(q3.z << 16);
        c1.y += e3 * __uint_as_float(q3.z & 0xffff0000u);
        c1.z += e3 * __uint_as_float(q3.w << 16);
        c1.w += e3 * __uint_as_float(q3.w & 0xffff0000u);
    }
    a0.x += c0.x; a0.y += c0.y; a0.z += c0.z; a0.w += c0.w;
    a1.x += c1.x; a1.y += c1.y; a1.z += c1.z; a1.w += c1.w;

    float r = 1.f / (den + 1e-16f);
    float4 b0 = *reinterpret_cast<const float4*>(bias + l * 8);
    float4 b1 = *reinterpret_cast<const float4*>(bias + l * 8 + 4);
    float4 v0, v1;
    v0.x = a0.x * r + b0.x; v0.y = a0.y * r + b0.y;
    v0.z = a0.z * r + b0.z; v0.w = a0.w * r + b0.w;
    v1.x = a1.x * r + b1.x; v1.y = a1.y * r + b1.y;
    v1.z = a1.z * r + b1.z; v1.w = a1.w * r + b1.w;
    v0.x = (v0.x > 0.f) ? v0.x : expm1f(v0.x);
    v0.y = (v0.y > 0.f) ? v0.y : expm1f(v0.y);
    v0.z = (v0.z > 0.f) ? v0.z : expm1f(v0.z);
    v0.w = (v0.w > 0.f) ? v0.w : expm1f(v0.w);
    v1.x = (v1.x > 0.f) ? v1.x : expm1f(v1.x);
    v1.y = (v1.y > 0.f) ? v1.y : expm1f(v1.y);
    v1.z = (v1.z > 0.f) ? v1.z : expm1f(v1.z);
    v1.w = (v1.w > 0.f) ? v1.w : expm1f(v1.w);

    uint4 u;
    u.x = (unsigned)bf16_rne(v0.x) | ((unsigned)bf16_rne(v0.y) << 16);
    u.y = (unsigned)bf16_rne(v0.z) | ((unsigned)bf16_rne(v0.w) << 16);
    u.z = (unsigned)bf16_rne(v1.x) | ((unsigned)bf16_rne(v1.y) << 16);
    u.w = (unsigned)bf16_rne(v1.z) | ((unsigned)bf16_rne(v1.w) << 16);
    *reinterpret_cast<uint4*>(outbf + (size_t)d * 128 + l * 8) = u;
}

// ===== layer 2: single-pass softmax + split aggr + log_softmax (perm'd) =====
__global__ __launch_bounds__(256) void gat40_k(
        const int* __restrict__ perm, const int* __restrict__ begA, const int* __restrict__ endA,
        const int* __restrict__ cols, const unsigned short* __restrict__ H32,
        const unsigned short* __restrict__ H8, const float* __restrict__ ssrc,
        const float* __restrict__ sdst, const float* __restrict__ b2,
        float* __restrict__ out, int n) {
    int g = (blockIdx.x * 256 + threadIdx.x) >> 4;
    if (g >= n) return;
    int d = perm[g];
    int l = threadIdx.x & 15;
    int beg = begA[d], end = endA[d];
    float sd = sdst[d];

    bool lo32 = (l < 8);
    int o32 = l * 4;
    int o8  = ((l >= 8 && l < 10) ? (l - 8) : 0) * 4;

    float4 acc = {0.f, 0.f, 0.f, 0.f};
    float4 acc2 = {0.f, 0.f, 0.f, 0.f};
    float den = 0.f;

    auto proc = [&](int i, float4& p) {
        int s = cols[i];
        float v = ssrc[s] + sd;
        v = (v >= 0.f) ? v : NEG_SLOPE * v;
        float a = __expf(v);
        den += a;
        const unsigned short* hp = lo32 ? (H32 + (size_t)s * 32 + o32)
                                        : (H8  + (size_t)s * 8  + o8);
        uint2 q = *reinterpret_cast<const uint2*>(hp);
        p.x += a * __uint_as_float(q.x << 16);
        p.y += a * __uint_as_float(q.x & 0xffff0000u);
        p.z += a * __uint_as_float(q.y << 16);
        p.w += a * __uint_as_float(q.y & 0xffff0000u);
    };
    int i = beg;
    int rem = (end - beg) & 3;
    if (rem & 1) { proc(i, acc); ++i; }
    if (rem & 2) { proc(i, acc); proc(i + 1, acc2); i += 2; }
    for (; i < end; i += 4) {
        int s0 = cols[i], s1 = cols[i + 1], s2 = cols[i + 2], s3 = cols[i + 3];
        float w0 = ssrc[s0] + sd, w1 = ssrc[s1] + sd;
        float w2 = ssrc[s2] + sd, w3 = ssrc[s3] + sd;
        const unsigned short* p0 = lo32 ? (H32 + (size_t)s0 * 32 + o32) : (H8 + (size_t)s0 * 8 + o8);
        const unsigned short* p1 = lo32 ? (H32 + (size_t)s1 * 32 + o32) : (H8 + (size_t)s1 * 8 + o8);
        const unsigned short* p2 = lo32 ? (H32 + (size_t)s2 * 32 + o32) : (H8 + (size_t)s2 * 8 + o8);
        const unsigned short* p3 = lo32 ? (H32 + (size_t)s3 * 32 + o32) : (H8 + (size_t)s3 * 8 + o8);
        uint2 q0 = *reinterpret_cast<const uint2*>(p0);
        uint2 q1 = *reinterpret_cast<const uint2*>(p1);
        uint2 q2 = *reinterpret_cast<const uint2*>(p2);
        uint2 q3 = *reinterpret_cast<const uint2*>(p3);
        w0 = (w0 >= 0.f) ? w0 : NEG_SLOPE * w0;
        w1 = (w1 >= 0.f) ? w1 : NEG_SLOPE * w1;
        w2 = (w2 >= 0.f) ? w2 : NEG_SLOPE * w2;
        w3 = (w3 >= 0.f) ? w3 : NEG_SLOPE * w3;
        float e0 = __expf(w0), e1 = __expf(w1);
        float e2 = __expf(w2), e3 = __expf(w3);
        den += e0 + e1 + e2 + e3;
        acc.x += e0 * __uint_as_float(q0.x << 16);
        acc.y += e0 * __uint_as_float(q0.x & 0xffff0000u);
        acc.z += e0 * __uint_as_float(q0.y << 16);
        acc.w += e0 * __uint_as_float(q0.y & 0xffff0000u);
        acc2.x += e1 * __uint_as_float(q1.x << 16);
        acc2.y += e1 * __uint_as_float(q1.x & 0xffff0000u);
        acc2.z += e1 * __uint_as_float(q1.y << 16);
        acc2.w += e1 * __uint_as_float(q1.y & 0xffff0000u);
        acc.x += e2 * __uint_as_float(q2.x << 16);
        acc.y += e2 * __uint_as_float(q2.x & 0xffff0000u);
        acc.z += e2 * __uint_as_float(q2.y << 16);
        acc.w += e2 * __uint_as_float(q2.y & 0xffff0000u);
        acc2.x += e3 * __uint_as_float(q3.x << 16);
        acc2.y += e3 * __uint_as_float(q3.x & 0xffff0000u);
        acc2.z += e3 * __uint_as_float(q3.y << 16);
        acc2.w += e3 * __uint_as_float(q3.y & 0xffff0000u);
    }
    acc.x += acc2.x; acc.y += acc2.y; acc.z += acc2.z; acc.w += acc2.w;

    float r = 1.f / (den + 1e-16f);
    float4 v4 = {0.f, 0.f, 0.f, 0.f};
    float mm = -1e30f;
    if (l < 10) {
        float4 b = *reinterpret_cast<const float4*>(b2 + l * 4);
        v4.x = acc.x * r + b.x; v4.y = acc.y * r + b.y;
        v4.z = acc.z * r + b.z; v4.w = acc.w * r + b.w;
        mm = fmaxf(fmaxf(v4.x, v4.y), fmaxf(v4.z, v4.w));
    }
    for (int off = 8; off > 0; off >>= 1) mm = fmaxf(mm, __shfl_xor(mm, off, 16));
    float ss = 0.f;
    if (l < 10)
        ss = __expf(v4.x - mm) + __expf(v4.y - mm) + __expf(v4.z - mm) + __expf(v4.w - mm);
    for (int off = 8; off > 0; off >>= 1) ss += __shfl_xor(ss, off, 16);
    float lse = mm + logf(ss);
    if (l < 10) {
        float4 o;
        o.x = v4.x - lse; o.y = v4.y - lse; o.z = v4.z - lse; o.w = v4.w - lse;
        *reinterpret_cast<float4*>(out + (size_t)d * 40 + l * 4) = o;
    }
}

static inline dim3 g1(long t) { return dim3((unsigned)((t + 255) / 256)); }

extern "C" void kernel_launch(void* const* d_in, const int* in_sizes, int n_in,
                              void* d_out, int out_size, void* d_ws, size_t ws_size,
                              hipStream_t stream) {
    const float* x      = (const float*)d_in[0];
    const int*   ei     = (const int*)d_in[1];
    const float* W0     = (const float*)d_in[2];
    const float* a_src0 = (const float*)d_in[3];
    const float* a_dst0 = (const float*)d_in[4];
    const float* b0     = (const float*)d_in[5];
    const float* W1     = (const float*)d_in[6];
    const float* a_src1 = (const float*)d_in[7];
    const float* a_dst1 = (const float*)d_in[8];
    const float* b1     = (const float*)d_in[9];
    const float* W2     = (const float*)d_in[10];
    const float* a_src2 = (const float*)d_in[11];
    const float* a_dst2 = (const float*)d_in[12];
    const float* b2     = (const float*)d_in[13];

    const int N    = in_sizes[0] / FIN;
    const int E    = in_sizes[1] / 2;
    const int Etot = E + N;
    const int NB   = (N + BKT - 1) / BKT;

    float* ws = (float*)d_ws;
    size_t o = 0;
    unsigned short* Hbf = (unsigned short*)(ws + o); o += (size_t)N * FIN / 2;
    unsigned short* Obf = (unsigned short*)(ws + o); o += (size_t)N * FIN / 2;
    unsigned short* H8  = (unsigned short*)(ws + o); o += (size_t)N * 4;
    float* ssrcA = ws + o; o += (size_t)N * HEADS;
    float* sdstA = ws + o; o += (size_t)N * HEADS;
    float* ssrcB = ws + o; o += (size_t)N * HEADS;
    float* sdstB = ws + o; o += (size_t)N * HEADS;
    int* gcur1  = (int*)(ws + o); o += NB_MAX;
    int* degcnt = (int*)(ws + o); o += 256;
    int* degcur = (int*)(ws + o); o += 256;
    int* begA   = (int*)(ws + o); o += N;
    int* endA   = (int*)(ws + o); o += N;
    int* perm   = (int*)(ws + o); o += N;
    int* cols   = (int*)(ws + o); o += (size_t)NB_MAX * CAP;
    unsigned* pairs = (unsigned*)(ws + o); o += (size_t)NB_MAX * CAP;
    unsigned short* Bhi0 = (unsigned short*)(ws + o); o += 4 * 8 * 64 * 8 / 2;
    unsigned short* Blo0 = (unsigned short*)(ws + o); o += 4 * 8 * 64 * 8 / 2;
    unsigned short* Bhi1 = (unsigned short*)(ws + o); o += 4 * 8 * 64 * 8 / 2;
    unsigned short* Blo1 = (unsigned short*)(ws + o); o += 4 * 8 * 64 * 8 / 2;
    unsigned short* Bhi2 = (unsigned short*)(ws + o); o += 4 * 3 * 64 * 8 / 2;
    unsigned short* Blo2 = (unsigned short*)(ws + o); o += 4 * 3 * 64 * 8 / 2;
    unsigned short* Shi0 = (unsigned short*)(ws + o); o += 4 * 64 * 8 / 2;
    unsigned short* Slo0 = (unsigned short*)(ws + o); o += 4 * 64 * 8 / 2;
    unsigned short* Shi1 = (unsigned short*)(ws + o); o += 4 * 64 * 8 / 2;
    unsigned short* Slo1 = (unsigned short*)(ws + o); o += 4 * 64 * 8 / 2;
    unsigned short* Shi2 = (unsigned short*)(ws + o); o += 4 * 64 * 8 / 2;
    unsigned short* Slo2 = (unsigned short*)(ws + o); o += 4 * 64 * 8 / 2;

    const int gemmBlocks = (N + 127) / 128;
    const int grpBlocks  = (N * 16 + 255) / 256;
    const int eTiles     = (Etot + TILE_E - 1) / TILE_E;

    // ---------------- setup: pack + one-pass CSR + degree sort --------------
    packAll_k<<<g1(45056 + NB_MAX + 256), 256, 0, stream>>>(
        W0, W1, W2, a_src0, a_dst0, a_src1, a_dst1, a_src2, a_dst2,
        Bhi0, Blo0, Bhi1, Blo1, Bhi2, Blo2,
        Shi0, Slo0, Shi1, Slo1, Shi2, Slo2, gcur1, degcnt);
    placeA_k<<<eTiles, 256, 0, stream>>>(ei, E, Etot, NB, gcur1, pairs);
    buildcsr_k<<<NB, 256, 0, stream>>>(pairs, gcur1, begA, endA, cols, degcnt, N);
    scanDeg_k<<<1, 256, 0, stream>>>(degcnt, degcur);
    permScatter_k<<<g1(N), 256, 0, stream>>>(begA, endA, degcur, perm, N);

    // ---------------- Layer 0 ----------------------------------------------
    gemm_fused_k<8, 4><<<gemmBlocks, 256, 0, stream>>>(x, Bhi0, Blo0, Shi0, Slo0, Hbf, ssrcA, sdstA, N, 128);
    gat128_k<<<grpBlocks, 256, 0, stream>>>(perm, begA, endA, cols, Hbf, ssrcA, sdstA, b0, Obf, N);

    // ---------------- Layer 1 ----------------------------------------------
    gemm_bf16s_k<8, 4, false><<<gemmBlocks, 256, 0, stream>>>(Obf, Bhi1, Blo1, Shi1, Slo1, Hbf, nullptr, ssrcB, sdstB, N, 128);
    gat128_k<<<grpBlocks, 256, 0, stream>>>(perm, begA, endA, cols, Hbf, ssrcB, sdstB, b1, Obf, N);

    // ---------------- Layer 2 (split H32/H8; fused log_softmax) -------------
    gemm_bf16s_k<3, 1, true><<<gemmBlocks, 256, 0, stream>>>(Obf, Bhi2, Blo2, Shi2, Slo2, Hbf, H8, ssrcA, sdstA, N, NCLS);
    gat40_k<<<grpBlocks, 256, 0, stream>>>(perm, begA, endA, cols, Hbf, H8, ssrcA, sdstA, b2, (float*)d_out, N);
}

// Round 16
// 316.189 us; speedup vs baseline: 2.9379x; 2.9379x over previous
//
#include <hip/hip_runtime.h>
#include <hip/hip_bf16.h>

#define FIN   128
#define HEADS 4
#define HID   32
#define NCLS  40
#define NEG_SLOPE 0.2f

#define BKT_SH 10
#define BKT    1024
#define NB_MAX 128
#define TILE_E 8192
#define CAP_SH 14
#define CAP    16384        // per-bucket pairs/cols capacity

typedef __bf16 bf16x8 __attribute__((ext_vector_type(8)));
typedef float  f32x4  __attribute__((ext_vector_type(4)));

__device__ inline unsigned short bf16_rne(float f) {
    unsigned u = __float_as_uint(f);
    return (unsigned short)((u + 0x7fffu + ((u >> 16) & 1u)) >> 16);
}
__device__ inline float bf16_to_f(unsigned short h) {
    return __uint_as_float(((unsigned)h) << 16);
}

// ===== packing device helpers ===============================================
__device__ inline void packW_dev(const float* __restrict__ W, unsigned short* __restrict__ Bhi,
                                 unsigned short* __restrict__ Blo, int NO, int NC, int idx) {
    int i = idx & 7;
    int rest = idx >> 3;
    int l = rest & 63;
    int rest2 = rest >> 6;
    int c = rest2 % NC;
    int t = rest2 / NC;
    int k   = t * 32 + (l >> 4) * 8 + i;
    int col = c * 16 + (l & 15);
    float val = (col < NO) ? W[(size_t)k * NO + col] : 0.f;
    unsigned short hi = bf16_rne(val);
    unsigned short lo = bf16_rne(val - bf16_to_f(hi));
    Bhi[idx] = hi;
    Blo[idx] = lo;
}

__device__ inline void packS_dev(const float* __restrict__ W, const float* __restrict__ asrc,
                                 const float* __restrict__ adst, unsigned short* __restrict__ Shi,
                                 unsigned short* __restrict__ Slo, int NO, int HH, int CH, int idx) {
    int i = idx & 7;
    int l = (idx >> 3) & 63;
    int t = idx >> 9;
    int k = t * 32 + (l >> 4) * 8 + i;
    int j = l & 15;
    float val = 0.f;
    if (j < 2 * HH) {
        int h = (j < HH) ? j : j - HH;
        const float* av = (j < HH) ? (asrc + h * CH) : (adst + h * CH);
        const float* wr = W + (size_t)k * NO + h * CH;
        for (int c = 0; c < CH; ++c) val += wr[c] * av[c];
    }
    unsigned short hi = bf16_rne(val);
    unsigned short lo = bf16_rne(val - bf16_to_f(hi));
    Shi[idx] = hi;
    Slo[idx] = lo;
}

// all W/S packing + gcur1 init (bucket bases) + degcnt zeroing
__global__ __launch_bounds__(256) void packAll_k(
        const float* __restrict__ W0, const float* __restrict__ W1, const float* __restrict__ W2,
        const float* __restrict__ as0, const float* __restrict__ ad0,
        const float* __restrict__ as1, const float* __restrict__ ad1,
        const float* __restrict__ as2, const float* __restrict__ ad2,
        unsigned short* __restrict__ Bhi0, unsigned short* __restrict__ Blo0,
        unsigned short* __restrict__ Bhi1, unsigned short* __restrict__ Blo1,
        unsigned short* __restrict__ Bhi2, unsigned short* __restrict__ Blo2,
        unsigned short* __restrict__ Shi0, unsigned short* __restrict__ Slo0,
        unsigned short* __restrict__ Shi1, unsigned short* __restrict__ Slo1,
        unsigned short* __restrict__ Shi2, unsigned short* __restrict__ Slo2,
        int* __restrict__ gcur1, int* __restrict__ degcnt) {
    int gid = blockIdx.x * 256 + threadIdx.x;
    if      (gid < 16384) packW_dev(W0, Bhi0, Blo0, 128, 8, gid);
    else if (gid < 32768) packW_dev(W1, Bhi1, Blo1, 128, 8, gid - 16384);
    else if (gid < 38912) packW_dev(W2, Bhi2, Blo2, NCLS, 3, gid - 32768);
    else if (gid < 40960) packS_dev(W0, as0, ad0, Shi0, Slo0, 128, 4, HID, gid - 38912);
    else if (gid < 43008) packS_dev(W1, as1, ad1, Shi1, Slo1, 128, 4, HID, gid - 40960);
    else if (gid < 45056) packS_dev(W2, as2, ad2, Shi2, Slo2, NCLS, 1, NCLS, gid - 43008);
    else if (gid < 45056 + NB_MAX) gcur1[gid - 45056] = (gid - 45056) << CAP_SH;
    else if (gid < 45056 + NB_MAX + 256) degcnt[gid - 45056 - NB_MAX] = 0;
}

// ===== layer-0 fused GEMM + scores (fp32 X, split-A) ========================
template<int NC, int HH>
__global__ __launch_bounds__(256) void gemm_fused_k(
        const float* __restrict__ X, const unsigned short* __restrict__ Bhi,
        const unsigned short* __restrict__ Blo, const unsigned short* __restrict__ Shi,
        const unsigned short* __restrict__ Slo, unsigned short* __restrict__ Hbf,
        float* __restrict__ ssrc, float* __restrict__ sdst, int n, int NO) {
    int wave = threadIdx.x >> 6;
    int lane = threadIdx.x & 63;
    int rowbase = (blockIdx.x * 4 + wave) * 32;
    if (rowbase >= n) return;
    int r0 = lane & 15, kg = lane >> 4;

    f32x4 acc[2][NC];
    f32x4 accS[2];
#pragma unroll
    for (int rt = 0; rt < 2; ++rt) {
        accS[rt] = f32x4{0.f, 0.f, 0.f, 0.f};
#pragma unroll
        for (int c = 0; c < NC; ++c) acc[rt][c] = f32x4{0.f, 0.f, 0.f, 0.f};
    }

    for (int t = 0; t < 4; ++t) {
        union U { unsigned short u[8]; bf16x8 v; };
        U ah[2], al[2];
#pragma unroll
        for (int rt = 0; rt < 2; ++rt) {
            int row = min(rowbase + rt * 16 + r0, n - 1);
            const float* xp = X + (size_t)row * 128 + t * 32 + kg * 8;
            float4 xa = *reinterpret_cast<const float4*>(xp);
            float4 xb = *reinterpret_cast<const float4*>(xp + 4);
            float f[8] = {xa.x, xa.y, xa.z, xa.w, xb.x, xb.y, xb.z, xb.w};
#pragma unroll
            for (int i = 0; i < 8; ++i) {
                unsigned short h = bf16_rne(f[i]);
                ah[rt].u[i] = h;
                al[rt].u[i] = bf16_rne(f[i] - bf16_to_f(h));
            }
        }
#pragma unroll
        for (int c = 0; c < NC; ++c) {
            size_t boff = (((size_t)t * NC + c) * 64 + lane) * 8;
            bf16x8 bh = *reinterpret_cast<const bf16x8*>(Bhi + boff);
            bf16x8 bl = *reinterpret_cast<const bf16x8*>(Blo + boff);
#pragma unroll
            for (int rt = 0; rt < 2; ++rt) {
                acc[rt][c] = __builtin_amdgcn_mfma_f32_16x16x32_bf16(ah[rt].v, bh, acc[rt][c], 0, 0, 0);
                acc[rt][c] = __builtin_amdgcn_mfma_f32_16x16x32_bf16(al[rt].v, bh, acc[rt][c], 0, 0, 0);
                acc[rt][c] = __builtin_amdgcn_mfma_f32_16x16x32_bf16(ah[rt].v, bl, acc[rt][c], 0, 0, 0);
            }
        }
        {
            size_t soff = ((size_t)t * 64 + lane) * 8;
            bf16x8 sh = *reinterpret_cast<const bf16x8*>(Shi + soff);
            bf16x8 sl = *reinterpret_cast<const bf16x8*>(Slo + soff);
#pragma unroll
            for (int rt = 0; rt < 2; ++rt) {
                accS[rt] = __builtin_amdgcn_mfma_f32_16x16x32_bf16(ah[rt].v, sh, accS[rt], 0, 0, 0);
                accS[rt] = __builtin_amdgcn_mfma_f32_16x16x32_bf16(al[rt].v, sh, accS[rt], 0, 0, 0);
                accS[rt] = __builtin_amdgcn_mfma_f32_16x16x32_bf16(ah[rt].v, sl, accS[rt], 0, 0, 0);
            }
        }
    }

#pragma unroll
    for (int rt = 0; rt < 2; ++rt)
#pragma unroll
        for (int r = 0; r < 4; ++r) {
            int row = rowbase + rt * 16 + kg * 4 + r;
            if (row >= n) continue;
            if (HH == 4) {
                if (r0 < 4)      ssrc[(size_t)row * 4 + r0]       = accS[rt][r];
                else if (r0 < 8) sdst[(size_t)row * 4 + (r0 - 4)] = accS[rt][r];
            } else {
                if (r0 == 0)      ssrc[row] = accS[rt][r];
                else if (r0 == 1) sdst[row] = accS[rt][r];
            }
#pragma unroll
            for (int c = 0; c < NC; ++c) {
                int col = c * 16 + r0;
                if (col < NO)
                    Hbf[(size_t)row * NO + col] = bf16_rne(acc[rt][c][r]);
            }
        }
}

// ===== layers 1/2 GEMM: bf16 A + scores via MFMA; optional split-40 out =====
template<int NC, int HH, bool SPLIT>
__global__ __launch_bounds__(256) void gemm_bf16s_k(
        const unsigned short* __restrict__ Xbf, const unsigned short* __restrict__ Bhi,
        const unsigned short* __restrict__ Blo, const unsigned short* __restrict__ Shi,
        const unsigned short* __restrict__ Slo, unsigned short* __restrict__ Hbf,
        unsigned short* __restrict__ H8,
        float* __restrict__ ssrc, float* __restrict__ sdst, int n, int NO) {
    int wave = threadIdx.x >> 6;
    int lane = threadIdx.x & 63;
    int rowbase = (blockIdx.x * 4 + wave) * 32;
    if (rowbase >= n) return;
    int r0 = lane & 15, kg = lane >> 4;

    f32x4 acc[2][NC];
    f32x4 accS[2];
#pragma unroll
    for (int rt = 0; rt < 2; ++rt) {
        accS[rt] = f32x4{0.f, 0.f, 0.f, 0.f};
#pragma unroll
        for (int c = 0; c < NC; ++c) acc[rt][c] = f32x4{0.f, 0.f, 0.f, 0.f};
    }

    for (int t = 0; t < 4; ++t) {
        bf16x8 av[2];
#pragma unroll
        for (int rt = 0; rt < 2; ++rt) {
            int row = min(rowbase + rt * 16 + r0, n - 1);
            av[rt] = *reinterpret_cast<const bf16x8*>(Xbf + (size_t)row * 128 + t * 32 + kg * 8);
        }
#pragma unroll
        for (int c = 0; c < NC; ++c) {
            size_t boff = (((size_t)t * NC + c) * 64 + lane) * 8;
            bf16x8 bh = *reinterpret_cast<const bf16x8*>(Bhi + boff);
            bf16x8 bl = *reinterpret_cast<const bf16x8*>(Blo + boff);
#pragma unroll
            for (int rt = 0; rt < 2; ++rt) {
                acc[rt][c] = __builtin_amdgcn_mfma_f32_16x16x32_bf16(av[rt], bh, acc[rt][c], 0, 0, 0);
                acc[rt][c] = __builtin_amdgcn_mfma_f32_16x16x32_bf16(av[rt], bl, acc[rt][c], 0, 0, 0);
            }
        }
        {
            size_t soff = ((size_t)t * 64 + lane) * 8;
            bf16x8 sh = *reinterpret_cast<const bf16x8*>(Shi + soff);
            bf16x8 sl = *reinterpret_cast<const bf16x8*>(Slo + soff);
#pragma unroll
            for (int rt = 0; rt < 2; ++rt) {
                accS[rt] = __builtin_amdgcn_mfma_f32_16x16x32_bf16(av[rt], sh, accS[rt], 0, 0, 0);
                accS[rt] = __builtin_amdgcn_mfma_f32_16x16x32_bf16(av[rt], sl, accS[rt], 0, 0, 0);
            }
        }
    }

#pragma unroll
    for (int rt = 0; rt < 2; ++rt)
#pragma unroll
        for (int r = 0; r < 4; ++r) {
            int row = rowbase + rt * 16 + kg * 4 + r;
            if (row >= n) continue;
            if (HH == 4) {
                if (r0 < 4)      ssrc[(size_t)row * 4 + r0]       = accS[rt][r];
                else if (r0 < 8) sdst[(size_t)row * 4 + (r0 - 4)] = accS[rt][r];
            } else {
                if (r0 == 0)      ssrc[row] = accS[rt][r];
                else if (r0 == 1) sdst[row] = accS[rt][r];
            }
#pragma unroll
            for (int c = 0; c < NC; ++c) {
                int col = c * 16 + r0;
                if (col < NO) {
                    unsigned short b = bf16_rne(acc[rt][c][r]);
                    if (!SPLIT) {
                        Hbf[(size_t)row * 128 + col] = b;
                    } else {
                        if (col < 32) Hbf[(size_t)row * 32 + col] = b;
                        else          H8[(size_t)row * 8 + (col - 32)] = b;
                    }
                }
            }
        }
}

// ===== CSR build: one-pass bucket partition (fixed CAP), beg/end rows =======
__global__ __launch_bounds__(256) void placeA_k(const int* __restrict__ ei, int E, int Etot,
                                                int nb, int* __restrict__ gcur1,
                                                unsigned* __restrict__ pairs) {
    __shared__ int h[NB_MAX];
    __shared__ int cur[NB_MAX];
    for (int i = threadIdx.x; i < nb; i += 256) h[i] = 0;
    __syncthreads();
    int base = blockIdx.x * TILE_E;
    int lim = min(base + TILE_E, Etot);
    for (int e = base + threadIdx.x; e < lim; e += 256) {
        int d = (e < E) ? ei[E + e] : e - E;
        atomicAdd(&h[d >> BKT_SH], 1);
    }
    __syncthreads();
    for (int i = threadIdx.x; i < nb; i += 256)
        cur[i] = h[i] ? atomicAdd(&gcur1[i], h[i]) : 0;
    __syncthreads();
    for (int e = base + threadIdx.x; e < lim; e += 256) {
        int s, d;
        if (e < E) { s = ei[e]; d = ei[E + e]; } else { s = d = e - E; }
        int b = d >> BKT_SH;
        int p = atomicAdd(&cur[b], 1);
        if (p < ((b + 1) << CAP_SH))
            pairs[p] = ((unsigned)s << BKT_SH) | (unsigned)(d & (BKT - 1));
    }
}

// per-bucket finalize: LDS per-dst hist + scan; LDS degree-class histogram
// flushed once per (block,class) -> no hot global atomics
__global__ __launch_bounds__(256) void buildcsr_k(const unsigned* __restrict__ pairs,
                                                  const int* __restrict__ gcur1,
                                                  int* __restrict__ begA, int* __restrict__ endA,
                                                  int* __restrict__ cols, int* __restrict__ degcnt,
                                                  int n) {
    __shared__ int cnt[BKT];
    __shared__ int part[256];
    __shared__ int dh[256];
    int b = blockIdx.x;
    int base = b << CAP_SH;
    int d0 = b << BKT_SH;
    int nd = min(BKT, n - d0);
    int total = min(gcur1[b] - base, CAP);
    for (int i = threadIdx.x; i < nd; i += 256) cnt[i] = 0;
    dh[threadIdx.x] = 0;
    __syncthreads();
    for (int i = base + threadIdx.x; i < base + total; i += 256)
        atomicAdd(&cnt[pairs[i] & (BKT - 1)], 1);
    __syncthreads();

    int t = threadIdx.x;
    int i4 = t * 4;
    int myv[4];
    int s0 = 0;
#pragma unroll
    for (int j = 0; j < 4; ++j) { myv[j] = (i4 + j < nd) ? cnt[i4 + j] : 0; s0 += myv[j]; }
    part[t] = s0;
    __syncthreads();
    for (int off = 1; off < 256; off <<= 1) {
        int tv = (t >= off) ? part[t - off] : 0;
        __syncthreads();
        part[t] += tv;
        __syncthreads();
    }
    int run = base + part[t] - s0;
#pragma unroll
    for (int j = 0; j < 4; ++j) {
        if (i4 + j < nd) {
            begA[d0 + i4 + j] = run;
            endA[d0 + i4 + j] = run + myv[j];
            atomicAdd(&dh[min(myv[j], 255)], 1);   // LDS
            cnt[i4 + j] = run;
            run += myv[j];
        }
    }
    __syncthreads();
    if (dh[t]) atomicAdd(&degcnt[t], dh[t]);       // one global atomic per class
    for (int i = base + threadIdx.x; i < base + total; i += 256) {
        unsigned p = pairs[i];
        int pos = atomicAdd(&cnt[p & (BKT - 1)], 1);
        cols[pos] = (int)(p >> BKT_SH);
    }
}

// exclusive scan of 256 degree-class counts -> class cursors
__global__ void scanDeg_k(const int* __restrict__ degcnt, int* __restrict__ degcur) {
    __shared__ int tmp[256];
    int l = threadIdx.x;
    int v = degcnt[l];
    tmp[l] = v;
    __syncthreads();
    for (int off = 1; off < 256; off <<= 1) {
        int t = (l >= off) ? tmp[l - off] : 0;
        __syncthreads();
        tmp[l] += t;
        __syncthreads();
    }
    degcur[l] = tmp[l] - v;
}

// scatter nodes into degree-sorted order; per-block LDS hist + chunk reserve
__global__ __launch_bounds__(256) void permScatter_k(const int* __restrict__ begA,
                                                     const int* __restrict__ endA,
                                                     int* __restrict__ degcur,
                                                     int* __restrict__ perm, int n) {
    __shared__ int h[256];
    __shared__ int cur[256];
    int d = blockIdx.x * 256 + threadIdx.x;
    int cls = -1;
    h[threadIdx.x] = 0;
    __syncthreads();
    if (d < n) {
        cls = min(endA[d] - begA[d], 255);
        atomicAdd(&h[cls], 1);
    }
    __syncthreads();
    int c = threadIdx.x;
    cur[c] = h[c] ? atomicAdd(&degcur[c], h[c]) : 0;
    __syncthreads();
    if (d < n) {
        int pos = atomicAdd(&cur[cls], 1);
        perm[pos] = d;
    }
}

// ===== layers 0/1: single-pass unnormalized softmax + bf16 aggr (perm'd) ====
__global__ __launch_bounds__(256) void gat128_k(
        const int* __restrict__ perm, const int* __restrict__ begA, const int* __restrict__ endA,
        const int* __restrict__ cols, const unsigned short* __restrict__ Hbf,
        const float* __restrict__ ssrc, const float* __restrict__ sdst,
        const float* __restrict__ bias, unsigned short* __restrict__ outbf, int n) {
    int g = (blockIdx.x * 256 + threadIdx.x) >> 4;
    if (g >= n) return;
    int d = perm[g];
    int l = threadIdx.x & 15;
    int head = l >> 2;
    int beg = begA[d], end = endA[d];

    float sdh = sdst[(size_t)d * 4 + head];

    float4 a0 = {0.f, 0.f, 0.f, 0.f}, a1 = {0.f, 0.f, 0.f, 0.f};
    float4 c0 = {0.f, 0.f, 0.f, 0.f}, c1 = {0.f, 0.f, 0.f, 0.f};
    float den = 0.f;

    auto proc = [&](int i, float4& p0, float4& p1) {
        int s = cols[i];
        float v = ssrc[(size_t)s * 4 + head] + sdh;
        v = (v >= 0.f) ? v : NEG_SLOPE * v;
        float a = __expf(v);
        den += a;
        const unsigned short* hp = Hbf + (size_t)s * 128 + l * 8;
        uint4 q = *reinterpret_cast<const uint4*>(hp);
        p0.x += a * __uint_as_float(q.x << 16);
        p0.y += a * __uint_as_float(q.x & 0xffff0000u);
        p0.z += a * __uint_as_float(q.y << 16);
        p0.w += a * __uint_as_float(q.y & 0xffff0000u);
        p1.x += a * __uint_as_float(q.z << 16);
        p1.y += a * __uint_as_float(q.z & 0xffff0000u);
        p1.z += a * __uint_as_float(q.w << 16);
        p1.w += a * __uint_as_float(q.w & 0xffff0000u);
    };

    int i = beg;
    int rem = (end - beg) & 3;
    if (rem & 1) { proc(i, a0, a1); ++i; }
    if (rem & 2) { proc(i, a0, a1); proc(i + 1, c0, c1); i += 2; }
    for (; i < end; i += 4) {
        int s0 = cols[i], s1 = cols[i + 1], s2 = cols[i + 2], s3 = cols[i + 3];
        float w0 = ssrc[(size_t)s0 * 4 + head] + sdh;
        float w1 = ssrc[(size_t)s1 * 4 + head] + sdh;
        float w2 = ssrc[(size_t)s2 * 4 + head] + sdh;
        float w3 = ssrc[(size_t)s3 * 4 + head] + sdh;
        uint4 q0 = *reinterpret_cast<const uint4*>(Hbf + (size_t)s0 * 128 + l * 8);
        uint4 q1 = *reinterpret_cast<const uint4*>(Hbf + (size_t)s1 * 128 + l * 8);
        uint4 q2 = *reinterpret_cast<const uint4*>(Hbf + (size_t)s2 * 128 + l * 8);
        uint4 q3 = *reinterpret_cast<const uint4*>(Hbf + (size_t)s3 * 128 + l * 8);
        w0 = (w0 >= 0.f) ? w0 : NEG_SLOPE * w0;
        w1 = (w1 >= 0.f) ? w1 : NEG_SLOPE * w1;
        w2 = (w2 >= 0.f) ? w2 : NEG_SLOPE * w2;
        w3 = (w3 >= 0.f) ? w3 : NEG_SLOPE * w3;
        float e0 = __expf(w0), e1 = __expf(w1);
        float e2 = __expf(w2), e3 = __expf(w3);
        den += e0 + e1 + e2 + e3;
        a0.x += e0 * __uint_as_float(q0.x << 16);
        a0.y += e0 * __uint_as_float(q0.x & 0xffff0000u);
        a0.z += e0 * __uint_as_float(q0.y << 16);
        a0.w += e0 * __uint_as_float(q0.y & 0xffff0000u);
        a1.x += e0 * __uint_as_float(q0.z << 16);
        a1.y += e0 * __uint_as_float(q0.z & 0xffff0000u);
        a1.z += e0 * __uint_as_float(q0.w << 16);
        a1.w += e0 * __uint_as_float(q0.w & 0xffff0000u);
        c0.x += e1 * __uint_as_float(q1.x << 16);
        c0.y += e1 * __uint_as_float(q1.x & 0xffff0000u);
        c0.z += e1 * __uint_as_float(q1.y << 16);
        c0.w += e1 * __uint_as_float(q1.y & 0xffff0000u);
        c1.x += e1 * __uint_as_float(q1.z << 16);
        c1.y += e1 * __uint_as_float(q1.z & 0xffff0000u);
        c1.z += e1 * __uint_as_float(q1.w << 16);
        c1.w += e1 * __uint_as_float(q1.w & 0xffff0000u);
        a0.x += e2 * __uint_as_float(q2.x << 16);
        a0.y += e2 * __uint_as_float(q2.x & 0xffff0000u);
        a0.z += e2 * __uint_as_float(q2.y << 16);
        a0.w += e2 * __uint_as_float(q2.y & 0xffff0000u);
        a1.x += e2 * __uint_as_float(q2.z << 16);
        a1.y += e2 * __uint_as_float(q2.z & 0xffff0000u);
        a1.z += e2 * __uint_as_float(q2.w << 16);
        a1.w += e2 * __uint_as_float(q2.w & 0xffff0000u);
        c0.x += e3 * __uint_as_float(q3.x << 16);
        c0.y += e3 * __uint_as_float(q3.x & 0xffff0000u);
        c0.z += e3 * __uint_as_float(q3.y << 16);
        c0.w += e3 * __uint_as_float(q3.y & 0xffff0000u);
        c1.x += e3 * __uint_as_float(q3.z << 16);
        c1.y += e3 * __uint_as_float(q3.z & 0xffff0000u);
        c1.z += e3 * __uint_as_float(q3.w << 16);
        c1.w += e3 * __uint_as_float(q3.w & 0xffff0000u);
    }
    a0.x += c0.x; a0.y += c0.y; a0.z += c0.z; a0.w += c0.w;
    a1.x += c1.x; a1.y += c1.y; a1.z += c1.z; a1.w += c1.w;

    float r = 1.f / (den + 1e-16f);
    float4 b0 = *reinterpret_cast<const float4*>(bias + l * 8);
    float4 b1 = *reinterpret_cast<const float4*>(bias + l * 8 + 4);
    float4 v0, v1;
    v0.x = a0.x * r + b0.x; v0.y = a0.y * r + b0.y;
    v0.z = a0.z * r + b0.z; v0.w = a0.w * r + b0.w;
    v1.x = a1.x * r + b1.x; v1.y = a1.y * r + b1.y;
    v1.z = a1.z * r + b1.z; v1.w = a1.w * r + b1.w;
    v0.x = (v0.x > 0.f) ? v0.x : expm1f(v0.x);
    v0.y = (v0.y > 0.f) ? v0.y : expm1f(v0.y);
    v0.z = (v0.z > 0.f) ? v0.z : expm1f(v0.z);
    v0.w = (v0.w > 0.f) ? v0.w : expm1f(v0.w);
    v1.x = (v1.x > 0.f) ? v1.x : expm1f(v1.x);
    v1.y = (v1.y > 0.f) ? v1.y : expm1f(v1.y);
    v1.z = (v1.z > 0.f) ? v1.z : expm1f(v1.z);
    v1.w = (v1.w > 0.f) ? v1.w : expm1f(v1.w);

    uint4 u;
    u.x = (unsigned)bf16_rne(v0.x) | ((unsigned)bf16_rne(v0.y) << 16);
    u.y = (unsigned)bf16_rne(v0.z) | ((unsigned)bf16_rne(v0.w) << 16);
    u.z = (unsigned)bf16_rne(v1.x) | ((unsigned)bf16_rne(v1.y) << 16);
    u.w = (unsigned)bf16_rne(v1.z) | ((unsigned)bf16_rne(v1.w) << 16);
    *reinterpret_cast<uint4*>(outbf + (size_t)d * 128 + l * 8) = u;
}

// ===== layer 2: single-pass softmax + split aggr + log_softmax (perm'd) =====
__global__ __launch_bounds__(256) void gat40_k(
        const int* __restrict__ perm, const int* __restrict__ begA, const int* __restrict__ endA,
        const int* __restrict__ cols, const unsigned short* __restrict__ H32,
        const unsigned short* __restrict__ H8, const float* __restrict__ ssrc,
        const float* __restrict__ sdst, const float* __restrict__ b2,
        float* __restrict__ out, int n) {
    int g = (blockIdx.x * 256 + threadIdx.x) >> 4;
    if (g >= n) return;
    int d = perm[g];
    int l = threadIdx.x & 15;
    int beg = begA[d], end = endA[d];
    float sd = sdst[d];

    bool lo32 = (l < 8);
    int o32 = l * 4;
    int o8  = ((l >= 8 && l < 10) ? (l - 8) : 0) * 4;

    float4 acc = {0.f, 0.f, 0.f, 0.f};
    float4 acc2 = {0.f, 0.f, 0.f, 0.f};
    float den = 0.f;

    auto proc = [&](int i, float4& p) {
        int s = cols[i];
        float v = ssrc[s] + sd;
        v = (v >= 0.f) ? v : NEG_SLOPE * v;
        float a = __expf(v);
        den += a;
        const unsigned short* hp = lo32 ? (H32 + (size_t)s * 32 + o32)
                                        : (H8  + (size_t)s * 8  + o8);
        uint2 q = *reinterpret_cast<const uint2*>(hp);
        p.x += a * __uint_as_float(q.x << 16);
        p.y += a * __uint_as_float(q.x & 0xffff0000u);
        p.z += a * __uint_as_float(q.y << 16);
        p.w += a * __uint_as_float(q.y & 0xffff0000u);
    };
    int i = beg;
    int rem = (end - beg) & 3;
    if (rem & 1) { proc(i, acc); ++i; }
    if (rem & 2) { proc(i, acc); proc(i + 1, acc2); i += 2; }
    for (; i < end; i += 4) {
        int s0 = cols[i], s1 = cols[i + 1], s2 = cols[i + 2], s3 = cols[i + 3];
        float w0 = ssrc[s0] + sd, w1 = ssrc[s1] + sd;
        float w2 = ssrc[s2] + sd, w3 = ssrc[s3] + sd;
        const unsigned short* p0 = lo32 ? (H32 + (size_t)s0 * 32 + o32) : (H8 + (size_t)s0 * 8 + o8);
        const unsigned short* p1 = lo32 ? (H32 + (size_t)s1 * 32 + o32) : (H8 + (size_t)s1 * 8 + o8);
        const unsigned short* p2 = lo32 ? (H32 + (size_t)s2 * 32 + o32) : (H8 + (size_t)s2 * 8 + o8);
        const unsigned short* p3 = lo32 ? (H32 + (size_t)s3 * 32 + o32) : (H8 + (size_t)s3 * 8 + o8);
        uint2 q0 = *reinterpret_cast<const uint2*>(p0);
        uint2 q1 = *reinterpret_cast<const uint2*>(p1);
        uint2 q2 = *reinterpret_cast<const uint2*>(p2);
        uint2 q3 = *reinterpret_cast<const uint2*>(p3);
        w0 = (w0 >= 0.f) ? w0 : NEG_SLOPE * w0;
        w1 = (w1 >= 0.f) ? w1 : NEG_SLOPE * w1;
        w2 = (w2 >= 0.f) ? w2 : NEG_SLOPE * w2;
        w3 = (w3 >= 0.f) ? w3 : NEG_SLOPE * w3;
        float e0 = __expf(w0), e1 = __expf(w1);
        float e2 = __expf(w2), e3 = __expf(w3);
        den += e0 + e1 + e2 + e3;
        acc.x += e0 * __uint_as_float(q0.x << 16);
        acc.y += e0 * __uint_as_float(q0.x & 0xffff0000u);
        acc.z += e0 * __uint_as_float(q0.y << 16);
        acc.w += e0 * __uint_as_float(q0.y & 0xffff0000u);
        acc2.x += e1 * __uint_as_float(q1.x << 16);
        acc2.y += e1 * __uint_as_float(q1.x & 0xffff0000u);
        acc2.z += e1 * __uint_as_float(q1.y << 16);
        acc2.w += e1 * __uint_as_float(q1.y & 0xffff0000u);
        acc.x += e2 * __uint_as_float(q2.x << 16);
        acc.y += e2 * __uint_as_float(q2.x & 0xffff0000u);
        acc.z += e2 * __uint_as_float(q2.y << 16);
        acc.w += e2 * __uint_as_float(q2.y & 0xffff0000u);
        acc2.x += e3 * __uint_as_float(q3.x << 16);
        acc2.y += e3 * __uint_as_float(q3.x & 0xffff0000u);
        acc2.z += e3 * __uint_as_float(q3.y << 16);
        acc2.w += e3 * __uint_as_float(q3.y & 0xffff0000u);
    }
    acc.x += acc2.x; acc.y += acc2.y; acc.z += acc2.z; acc.w += acc2.w;

    float r = 1.f / (den + 1e-16f);
    float4 v4 = {0.f, 0.f, 0.f, 0.f};
    float mm = -1e30f;
    if (l < 10) {
        float4 b = *reinterpret_cast<const float4*>(b2 + l * 4);
        v4.x = acc.x * r + b.x; v4.y = acc.y * r + b.y;
        v4.z = acc.z * r + b.z; v4.w = acc.w * r + b.w;
        mm = fmaxf(fmaxf(v4.x, v4.y), fmaxf(v4.z, v4.w));
    }
    for (int off = 8; off > 0; off >>= 1) mm = fmaxf(mm, __shfl_xor(mm, off, 16));
    float ss = 0.f;
    if (l < 10)
        ss = __expf(v4.x - mm) + __expf(v4.y - mm) + __expf(v4.z - mm) + __expf(v4.w - mm);
    for (int off = 8; off > 0; off >>= 1) ss += __shfl_xor(ss, off, 16);
    float lse = mm + logf(ss);
    if (l < 10) {
        float4 o;
        o.x = v4.x - lse; o.y = v4.y - lse; o.z = v4.z - lse; o.w = v4.w - lse;
        *reinterpret_cast<float4*>(out + (size_t)d * 40 + l * 4) = o;
    }
}

static inline dim3 g1(long t) { return dim3((unsigned)((t + 255) / 256)); }

extern "C" void kernel_launch(void* const* d_in, const int* in_sizes, int n_in,
                              void* d_out, int out_size, void* d_ws, size_t ws_size,
                              hipStream_t stream) {
    const float* x      = (const float*)d_in[0];
    const int*   ei     = (const int*)d_in[1];
    const float* W0     = (const float*)d_in[2];
    const float* a_src0 = (const float*)d_in[3];
    const float* a_dst0 = (const float*)d_in[4];
    const float* b0     = (const float*)d_in[5];
    const float* W1     = (const float*)d_in[6];
    const float* a_src1 = (const float*)d_in[7];
    const float* a_dst1 = (const float*)d_in[8];
    const float* b1     = (const float*)d_in[9];
    const float* W2     = (const float*)d_in[10];
    const float* a_src2 = (const float*)d_in[11];
    const float* a_dst2 = (const float*)d_in[12];
    const float* b2     = (const float*)d_in[13];

    const int N    = in_sizes[0] / FIN;
    const int E    = in_sizes[1] / 2;
    const int Etot = E + N;
    const int NB   = (N + BKT - 1) / BKT;

    float* ws = (float*)d_ws;
    size_t o = 0;
    unsigned short* Hbf = (unsigned short*)(ws + o); o += (size_t)N * FIN / 2;
    unsigned short* Obf = (unsigned short*)(ws + o); o += (size_t)N * FIN / 2;
    unsigned short* H8  = (unsigned short*)(ws + o); o += (size_t)N * 4;
    float* ssrcA = ws + o; o += (size_t)N * HEADS;
    float* sdstA = ws + o; o += (size_t)N * HEADS;
    float* ssrcB = ws + o; o += (size_t)N * HEADS;
    float* sdstB = ws + o; o += (size_t)N * HEADS;
    int* gcur1  = (int*)(ws + o); o += NB_MAX;
    int* degcnt = (int*)(ws + o); o += 256;
    int* degcur = (int*)(ws + o); o += 256;
    int* begA   = (int*)(ws + o); o += N;
    int* endA   = (int*)(ws + o); o += N;
    int* perm   = (int*)(ws + o); o += N;
    int* cols   = (int*)(ws + o); o += (size_t)NB_MAX * CAP;
    unsigned* pairs = (unsigned*)(ws + o); o += (size_t)NB_MAX * CAP;
    unsigned short* Bhi0 = (unsigned short*)(ws + o); o += 4 * 8 * 64 * 8 / 2;
    unsigned short* Blo0 = (unsigned short*)(ws + o); o += 4 * 8 * 64 * 8 / 2;
    unsigned short* Bhi1 = (unsigned short*)(ws + o); o += 4 * 8 * 64 * 8 / 2;
    unsigned short* Blo1 = (unsigned short*)(ws + o); o += 4 * 8 * 64 * 8 / 2;
    unsigned short* Bhi2 = (unsigned short*)(ws + o); o += 4 * 3 * 64 * 8 / 2;
    unsigned short* Blo2 = (unsigned short*)(ws + o); o += 4 * 3 * 64 * 8 / 2;
    unsigned short* Shi0 = (unsigned short*)(ws + o); o += 4 * 64 * 8 / 2;
    unsigned short* Slo0 = (unsigned short*)(ws + o); o += 4 * 64 * 8 / 2;
    unsigned short* Shi1 = (unsigned short*)(ws + o); o += 4 * 64 * 8 / 2;
    unsigned short* Slo1 = (unsigned short*)(ws + o); o += 4 * 64 * 8 / 2;
    unsigned short* Shi2 = (unsigned short*)(ws + o); o += 4 * 64 * 8 / 2;
    unsigned short* Slo2 = (unsigned short*)(ws + o); o += 4 * 64 * 8 / 2;

    const int gemmBlocks = (N + 127) / 128;
    const int grpBlocks  = (N * 16 + 255) / 256;
    const int eTiles     = (Etot + TILE_E - 1) / TILE_E;

    // ---------------- setup: pack + one-pass CSR + degree sort --------------
    packAll_k<<<g1(45056 + NB_MAX + 256), 256, 0, stream>>>(
        W0, W1, W2, a_src0, a_dst0, a_src1, a_dst1, a_src2, a_dst2,
        Bhi0, Blo0, Bhi1, Blo1, Bhi2, Blo2,
        Shi0, Slo0, Shi1, Slo1, Shi2, Slo2, gcur1, degcnt);
    placeA_k<<<eTiles, 256, 0, stream>>>(ei, E, Etot, NB, gcur1, pairs);
    buildcsr_k<<<NB, 256, 0, stream>>>(pairs, gcur1, begA, endA, cols, degcnt, N);
    scanDeg_k<<<1, 256, 0, stream>>>(degcnt, degcur);
    permScatter_k<<<g1(N), 256, 0, stream>>>(begA, endA, degcur, perm, N);

    // ---------------- Layer 0 ----------------------------------------------
    gemm_fused_k<8, 4><<<gemmBlocks, 256, 0, stream>>>(x, Bhi0, Blo0, Shi0, Slo0, Hbf, ssrcA, sdstA, N, 128);
    gat128_k<<<grpBlocks, 256, 0, stream>>>(perm, begA, endA, cols, Hbf, ssrcA, sdstA, b0, Obf, N);

    // ---------------- Layer 1 ----------------------------------------------
    gemm_bf16s_k<8, 4, false><<<gemmBlocks, 256, 0, stream>>>(Obf, Bhi1, Blo1, Shi1, Slo1, Hbf, nullptr, ssrcB, sdstB, N, 128);
    gat128_k<<<grpBlocks, 256, 0, stream>>>(perm, begA, endA, cols, Hbf, ssrcB, sdstB, b1, Obf, N);

    // ---------------- Layer 2 (split H32/H8; fused log_softmax) -------------
    gemm_bf16s_k<3, 1, true><<<gemmBlocks, 256, 0, stream>>>(Obf, Bhi2, Blo2, Shi2, Slo2, Hbf, H8, ssrcA, sdstA, N, NCLS);
    gat40_k<<<grpBlocks, 256, 0, stream>>>(perm, begA, endA, cols, Hbf, H8, ssrcA, sdstA, b2, (float*)d_out, N);
}

// Round 17
// 297.754 us; speedup vs baseline: 3.1198x; 1.0619x over previous
//
#include <hip/hip_runtime.h>
#include <hip/hip_bf16.h>

#define FIN   128
#define HEADS 4
#define HID   32
#define NCLS  40
#define NEG_SLOPE 0.2f

#define BKT_SH 10
#define BKT    1024
#define NB_MAX 128
#define TILE_E 8192
#define CAP_SH 14
#define CAP    16384        // per-bucket pairs/cols capacity

typedef __bf16 bf16x8 __attribute__((ext_vector_type(8)));
typedef float  f32x4  __attribute__((ext_vector_type(4)));

__device__ inline unsigned short bf16_rne(float f) {
    unsigned u = __float_as_uint(f);
    return (unsigned short)((u + 0x7fffu + ((u >> 16) & 1u)) >> 16);
}
__device__ inline float bf16_to_f(unsigned short h) {
    return __uint_as_float(((unsigned)h) << 16);
}

// ===== packing device helpers ===============================================
__device__ inline void packW_dev(const float* __restrict__ W, unsigned short* __restrict__ Bhi,
                                 unsigned short* __restrict__ Blo, int NO, int NC, int idx) {
    int i = idx & 7;
    int rest = idx >> 3;
    int l = rest & 63;
    int rest2 = rest >> 6;
    int c = rest2 % NC;
    int t = rest2 / NC;
    int k   = t * 32 + (l >> 4) * 8 + i;
    int col = c * 16 + (l & 15);
    float val = (col < NO) ? W[(size_t)k * NO + col] : 0.f;
    unsigned short hi = bf16_rne(val);
    unsigned short lo = bf16_rne(val - bf16_to_f(hi));
    Bhi[idx] = hi;
    Blo[idx] = lo;
}

__device__ inline void packS_dev(const float* __restrict__ W, const float* __restrict__ asrc,
                                 const float* __restrict__ adst, unsigned short* __restrict__ Shi,
                                 unsigned short* __restrict__ Slo, int NO, int HH, int CH, int idx) {
    int i = idx & 7;
    int l = (idx >> 3) & 63;
    int t = idx >> 9;
    int k = t * 32 + (l >> 4) * 8 + i;
    int j = l & 15;
    float val = 0.f;
    if (j < 2 * HH) {
        int h = (j < HH) ? j : j - HH;
        const float* av = (j < HH) ? (asrc + h * CH) : (adst + h * CH);
        const float* wr = W + (size_t)k * NO + h * CH;
        for (int c = 0; c < CH; ++c) val += wr[c] * av[c];
    }
    unsigned short hi = bf16_rne(val);
    unsigned short lo = bf16_rne(val - bf16_to_f(hi));
    Shi[idx] = hi;
    Slo[idx] = lo;
}

// all W/S packing + gcur1 init (bucket bases)
__global__ __launch_bounds__(256) void packAll_k(
        const float* __restrict__ W0, const float* __restrict__ W1, const float* __restrict__ W2,
        const float* __restrict__ as0, const float* __restrict__ ad0,
        const float* __restrict__ as1, const float* __restrict__ ad1,
        const float* __restrict__ as2, const float* __restrict__ ad2,
        unsigned short* __restrict__ Bhi0, unsigned short* __restrict__ Blo0,
        unsigned short* __restrict__ Bhi1, unsigned short* __restrict__ Blo1,
        unsigned short* __restrict__ Bhi2, unsigned short* __restrict__ Blo2,
        unsigned short* __restrict__ Shi0, unsigned short* __restrict__ Slo0,
        unsigned short* __restrict__ Shi1, unsigned short* __restrict__ Slo1,
        unsigned short* __restrict__ Shi2, unsigned short* __restrict__ Slo2,
        int* __restrict__ gcur1) {
    int gid = blockIdx.x * 256 + threadIdx.x;
    if      (gid < 16384) packW_dev(W0, Bhi0, Blo0, 128, 8, gid);
    else if (gid < 32768) packW_dev(W1, Bhi1, Blo1, 128, 8, gid - 16384);
    else if (gid < 38912) packW_dev(W2, Bhi2, Blo2, NCLS, 3, gid - 32768);
    else if (gid < 40960) packS_dev(W0, as0, ad0, Shi0, Slo0, 128, 4, HID, gid - 38912);
    else if (gid < 43008) packS_dev(W1, as1, ad1, Shi1, Slo1, 128, 4, HID, gid - 40960);
    else if (gid < 45056) packS_dev(W2, as2, ad2, Shi2, Slo2, NCLS, 1, NCLS, gid - 43008);
    else if (gid < 45056 + NB_MAX) gcur1[gid - 45056] = (gid - 45056) << CAP_SH;
}

// ===== layer-0 fused GEMM + scores (fp32 X, split-A) ========================
template<int NC, int HH>
__global__ __launch_bounds__(256) void gemm_fused_k(
        const float* __restrict__ X, const unsigned short* __restrict__ Bhi,
        const unsigned short* __restrict__ Blo, const unsigned short* __restrict__ Shi,
        const unsigned short* __restrict__ Slo, unsigned short* __restrict__ Hbf,
        float* __restrict__ ssrc, float* __restrict__ sdst, int n, int NO) {
    int wave = threadIdx.x >> 6;
    int lane = threadIdx.x & 63;
    int rowbase = (blockIdx.x * 4 + wave) * 32;
    if (rowbase >= n) return;
    int r0 = lane & 15, kg = lane >> 4;

    f32x4 acc[2][NC];
    f32x4 accS[2];
#pragma unroll
    for (int rt = 0; rt < 2; ++rt) {
        accS[rt] = f32x4{0.f, 0.f, 0.f, 0.f};
#pragma unroll
        for (int c = 0; c < NC; ++c) acc[rt][c] = f32x4{0.f, 0.f, 0.f, 0.f};
    }

    for (int t = 0; t < 4; ++t) {
        union U { unsigned short u[8]; bf16x8 v; };
        U ah[2], al[2];
#pragma unroll
        for (int rt = 0; rt < 2; ++rt) {
            int row = min(rowbase + rt * 16 + r0, n - 1);
            const float* xp = X + (size_t)row * 128 + t * 32 + kg * 8;
            float4 xa = *reinterpret_cast<const float4*>(xp);
            float4 xb = *reinterpret_cast<const float4*>(xp + 4);
            float f[8] = {xa.x, xa.y, xa.z, xa.w, xb.x, xb.y, xb.z, xb.w};
#pragma unroll
            for (int i = 0; i < 8; ++i) {
                unsigned short h = bf16_rne(f[i]);
                ah[rt].u[i] = h;
                al[rt].u[i] = bf16_rne(f[i] - bf16_to_f(h));
            }
        }
#pragma unroll
        for (int c = 0; c < NC; ++c) {
            size_t boff = (((size_t)t * NC + c) * 64 + lane) * 8;
            bf16x8 bh = *reinterpret_cast<const bf16x8*>(Bhi + boff);
            bf16x8 bl = *reinterpret_cast<const bf16x8*>(Blo + boff);
#pragma unroll
            for (int rt = 0; rt < 2; ++rt) {
                acc[rt][c] = __builtin_amdgcn_mfma_f32_16x16x32_bf16(ah[rt].v, bh, acc[rt][c], 0, 0, 0);
                acc[rt][c] = __builtin_amdgcn_mfma_f32_16x16x32_bf16(al[rt].v, bh, acc[rt][c], 0, 0, 0);
                acc[rt][c] = __builtin_amdgcn_mfma_f32_16x16x32_bf16(ah[rt].v, bl, acc[rt][c], 0, 0, 0);
            }
        }
        {
            size_t soff = ((size_t)t * 64 + lane) * 8;
            bf16x8 sh = *reinterpret_cast<const bf16x8*>(Shi + soff);
            bf16x8 sl = *reinterpret_cast<const bf16x8*>(Slo + soff);
#pragma unroll
            for (int rt = 0; rt < 2; ++rt) {
                accS[rt] = __builtin_amdgcn_mfma_f32_16x16x32_bf16(ah[rt].v, sh, accS[rt], 0, 0, 0);
                accS[rt] = __builtin_amdgcn_mfma_f32_16x16x32_bf16(al[rt].v, sh, accS[rt], 0, 0, 0);
                accS[rt] = __builtin_amdgcn_mfma_f32_16x16x32_bf16(ah[rt].v, sl, accS[rt], 0, 0, 0);
            }
        }
    }

#pragma unroll
    for (int rt = 0; rt < 2; ++rt)
#pragma unroll
        for (int r = 0; r < 4; ++r) {
            int row = rowbase + rt * 16 + kg * 4 + r;
            if (row >= n) continue;
            if (HH == 4) {
                if (r0 < 4)      ssrc[(size_t)row * 4 + r0]       = accS[rt][r];
                else if (r0 < 8) sdst[(size_t)row * 4 + (r0 - 4)] = accS[rt][r];
            } else {
                if (r0 == 0)      ssrc[row] = accS[rt][r];
                else if (r0 == 1) sdst[row] = accS[rt][r];
            }
#pragma unroll
            for (int c = 0; c < NC; ++c) {
                int col = c * 16 + r0;
                if (col < NO)
                    Hbf[(size_t)row * NO + col] = bf16_rne(acc[rt][c][r]);
            }
        }
}

// ===== layers 1/2 GEMM: bf16 A + scores via MFMA; optional split-40 out =====
template<int NC, int HH, bool SPLIT>
__global__ __launch_bounds__(256) void gemm_bf16s_k(
        const unsigned short* __restrict__ Xbf, const unsigned short* __restrict__ Bhi,
        const unsigned short* __restrict__ Blo, const unsigned short* __restrict__ Shi,
        const unsigned short* __restrict__ Slo, unsigned short* __restrict__ Hbf,
        unsigned short* __restrict__ H8,
        float* __restrict__ ssrc, float* __restrict__ sdst, int n, int NO) {
    int wave = threadIdx.x >> 6;
    int lane = threadIdx.x & 63;
    int rowbase = (blockIdx.x * 4 + wave) * 32;
    if (rowbase >= n) return;
    int r0 = lane & 15, kg = lane >> 4;

    f32x4 acc[2][NC];
    f32x4 accS[2];
#pragma unroll
    for (int rt = 0; rt < 2; ++rt) {
        accS[rt] = f32x4{0.f, 0.f, 0.f, 0.f};
#pragma unroll
        for (int c = 0; c < NC; ++c) acc[rt][c] = f32x4{0.f, 0.f, 0.f, 0.f};
    }

    for (int t = 0; t < 4; ++t) {
        bf16x8 av[2];
#pragma unroll
        for (int rt = 0; rt < 2; ++rt) {
            int row = min(rowbase + rt * 16 + r0, n - 1);
            av[rt] = *reinterpret_cast<const bf16x8*>(Xbf + (size_t)row * 128 + t * 32 + kg * 8);
        }
#pragma unroll
        for (int c = 0; c < NC; ++c) {
            size_t boff = (((size_t)t * NC + c) * 64 + lane) * 8;
            bf16x8 bh = *reinterpret_cast<const bf16x8*>(Bhi + boff);
            bf16x8 bl = *reinterpret_cast<const bf16x8*>(Blo + boff);
#pragma unroll
            for (int rt = 0; rt < 2; ++rt) {
                acc[rt][c] = __builtin_amdgcn_mfma_f32_16x16x32_bf16(av[rt], bh, acc[rt][c], 0, 0, 0);
                acc[rt][c] = __builtin_amdgcn_mfma_f32_16x16x32_bf16(av[rt], bl, acc[rt][c], 0, 0, 0);
            }
        }
        {
            size_t soff = ((size_t)t * 64 + lane) * 8;
            bf16x8 sh = *reinterpret_cast<const bf16x8*>(Shi + soff);
            bf16x8 sl = *reinterpret_cast<const bf16x8*>(Slo + soff);
#pragma unroll
            for (int rt = 0; rt < 2; ++rt) {
                accS[rt] = __builtin_amdgcn_mfma_f32_16x16x32_bf16(av[rt], sh, accS[rt], 0, 0, 0);
                accS[rt] = __builtin_amdgcn_mfma_f32_16x16x32_bf16(av[rt], sl, accS[rt], 0, 0, 0);
            }
        }
    }

#pragma unroll
    for (int rt = 0; rt < 2; ++rt)
#pragma unroll
        for (int r = 0; r < 4; ++r) {
            int row = rowbase + rt * 16 + kg * 4 + r;
            if (row >= n) continue;
            if (HH == 4) {
                if (r0 < 4)      ssrc[(size_t)row * 4 + r0]       = accS[rt][r];
                else if (r0 < 8) sdst[(size_t)row * 4 + (r0 - 4)] = accS[rt][r];
            } else {
                if (r0 == 0)      ssrc[row] = accS[rt][r];
                else if (r0 == 1) sdst[row] = accS[rt][r];
            }
#pragma unroll
            for (int c = 0; c < NC; ++c) {
                int col = c * 16 + r0;
                if (col < NO) {
                    unsigned short b = bf16_rne(acc[rt][c][r]);
                    if (!SPLIT) {
                        Hbf[(size_t)row * 128 + col] = b;
                    } else {
                        if (col < 32) Hbf[(size_t)row * 32 + col] = b;
                        else          H8[(size_t)row * 8 + (col - 32)] = b;
                    }
                }
            }
        }
}

// ===== CSR build: one-pass bucket partition (fixed CAP), beg/end rows =======
__global__ __launch_bounds__(256) void placeA_k(const int* __restrict__ ei, int E, int Etot,
                                                int nb, int* __restrict__ gcur1,
                                                unsigned* __restrict__ pairs) {
    __shared__ int h[NB_MAX];
    __shared__ int cur[NB_MAX];
    for (int i = threadIdx.x; i < nb; i += 256) h[i] = 0;
    __syncthreads();
    int base = blockIdx.x * TILE_E;
    int lim = min(base + TILE_E, Etot);
    for (int e = base + threadIdx.x; e < lim; e += 256) {
        int d = (e < E) ? ei[E + e] : e - E;
        atomicAdd(&h[d >> BKT_SH], 1);
    }
    __syncthreads();
    for (int i = threadIdx.x; i < nb; i += 256)
        cur[i] = h[i] ? atomicAdd(&gcur1[i], h[i]) : 0;
    __syncthreads();
    for (int e = base + threadIdx.x; e < lim; e += 256) {
        int s, d;
        if (e < E) { s = ei[e]; d = ei[E + e]; } else { s = d = e - E; }
        int b = d >> BKT_SH;
        int p = atomicAdd(&cur[b], 1);
        if (p < ((b + 1) << CAP_SH))
            pairs[p] = ((unsigned)s << BKT_SH) | (unsigned)(d & (BKT - 1));
    }
}

__global__ __launch_bounds__(256) void buildcsr_k(const unsigned* __restrict__ pairs,
                                                  const int* __restrict__ gcur1,
                                                  int* __restrict__ begA, int* __restrict__ endA,
                                                  int* __restrict__ cols, int n) {
    __shared__ int cnt[BKT];
    __shared__ int part[256];
    int b = blockIdx.x;
    int base = b << CAP_SH;
    int d0 = b << BKT_SH;
    int nd = min(BKT, n - d0);
    int total = min(gcur1[b] - base, CAP);
    for (int i = threadIdx.x; i < nd; i += 256) cnt[i] = 0;
    __syncthreads();
    for (int i = base + threadIdx.x; i < base + total; i += 256)
        atomicAdd(&cnt[pairs[i] & (BKT - 1)], 1);
    __syncthreads();

    int t = threadIdx.x;
    int i4 = t * 4;
    int myv[4];
    int s0 = 0;
#pragma unroll
    for (int j = 0; j < 4; ++j) { myv[j] = (i4 + j < nd) ? cnt[i4 + j] : 0; s0 += myv[j]; }
    part[t] = s0;
    __syncthreads();
    for (int off = 1; off < 256; off <<= 1) {
        int tv = (t >= off) ? part[t - off] : 0;
        __syncthreads();
        part[t] += tv;
        __syncthreads();
    }
    int run = base + part[t] - s0;
#pragma unroll
    for (int j = 0; j < 4; ++j) {
        if (i4 + j < nd) {
            begA[d0 + i4 + j] = run;
            endA[d0 + i4 + j] = run + myv[j];
            cnt[i4 + j] = run;
            run += myv[j];
        }
    }
    __syncthreads();
    for (int i = base + threadIdx.x; i < base + total; i += 256) {
        unsigned p = pairs[i];
        int pos = atomicAdd(&cnt[p & (BKT - 1)], 1);
        cols[pos] = (int)(p >> BKT_SH);
    }
}

// ===== layers 0/1: single-pass unnormalized softmax + bf16 aggr =============
__global__ __launch_bounds__(256) void gat128_k(
        const int* __restrict__ begA, const int* __restrict__ endA,
        const int* __restrict__ cols, const unsigned short* __restrict__ Hbf,
        const float* __restrict__ ssrc, const float* __restrict__ sdst,
        const float* __restrict__ bias, unsigned short* __restrict__ outbf, int n) {
    int d = (blockIdx.x * 256 + threadIdx.x) >> 4;
    if (d >= n) return;
    int l = threadIdx.x & 15;
    int head = l >> 2;
    int beg = begA[d], end = endA[d];

    float sdh = sdst[(size_t)d * 4 + head];

    float4 a0 = {0.f, 0.f, 0.f, 0.f}, a1 = {0.f, 0.f, 0.f, 0.f};
    float4 c0 = {0.f, 0.f, 0.f, 0.f}, c1 = {0.f, 0.f, 0.f, 0.f};
    float den = 0.f;

    auto proc = [&](int i, float4& p0, float4& p1) {
        int s = cols[i];
        float v = ssrc[(size_t)s * 4 + head] + sdh;
        v = (v >= 0.f) ? v : NEG_SLOPE * v;
        float a = __expf(v);
        den += a;
        const unsigned short* hp = Hbf + (size_t)s * 128 + l * 8;
        uint4 q = *reinterpret_cast<const uint4*>(hp);
        p0.x += a * __uint_as_float(q.x << 16);
        p0.y += a * __uint_as_float(q.x & 0xffff0000u);
        p0.z += a * __uint_as_float(q.y << 16);
        p0.w += a * __uint_as_float(q.y & 0xffff0000u);
        p1.x += a * __uint_as_float(q.z << 16);
        p1.y += a * __uint_as_float(q.z & 0xffff0000u);
        p1.z += a * __uint_as_float(q.w << 16);
        p1.w += a * __uint_as_float(q.w & 0xffff0000u);
    };

    int i = beg;
    int rem = (end - beg) & 3;
    if (rem & 1) { proc(i, a0, a1); ++i; }
    if (rem & 2) { proc(i, a0, a1); proc(i + 1, c0, c1); i += 2; }
    for (; i < end; i += 4) {
        int s0 = cols[i], s1 = cols[i + 1], s2 = cols[i + 2], s3 = cols[i + 3];
        float w0 = ssrc[(size_t)s0 * 4 + head] + sdh;
        float w1 = ssrc[(size_t)s1 * 4 + head] + sdh;
        float w2 = ssrc[(size_t)s2 * 4 + head] + sdh;
        float w3 = ssrc[(size_t)s3 * 4 + head] + sdh;
        uint4 q0 = *reinterpret_cast<const uint4*>(Hbf + (size_t)s0 * 128 + l * 8);
        uint4 q1 = *reinterpret_cast<const uint4*>(Hbf + (size_t)s1 * 128 + l * 8);
        uint4 q2 = *reinterpret_cast<const uint4*>(Hbf + (size_t)s2 * 128 + l * 8);
        uint4 q3 = *reinterpret_cast<const uint4*>(Hbf + (size_t)s3 * 128 + l * 8);
        w0 = (w0 >= 0.f) ? w0 : NEG_SLOPE * w0;
        w1 = (w1 >= 0.f) ? w1 : NEG_SLOPE * w1;
        w2 = (w2 >= 0.f) ? w2 : NEG_SLOPE * w2;
        w3 = (w3 >= 0.f) ? w3 : NEG_SLOPE * w3;
        float e0 = __expf(w0), e1 = __expf(w1);
        float e2 = __expf(w2), e3 = __expf(w3);
        den += e0 + e1 + e2 + e3;
        a0.x += e0 * __uint_as_float(q0.x << 16);
        a0.y += e0 * __uint_as_float(q0.x & 0xffff0000u);
        a0.z += e0 * __uint_as_float(q0.y << 16);
        a0.w += e0 * __uint_as_float(q0.y & 0xffff0000u);
        a1.x += e0 * __uint_as_float(q0.z << 16);
        a1.y += e0 * __uint_as_float(q0.z & 0xffff0000u);
        a1.z += e0 * __uint_as_float(q0.w << 16);
        a1.w += e0 * __uint_as_float(q0.w & 0xffff0000u);
        c0.x += e1 * __uint_as_float(q1.x << 16);
        c0.y += e1 * __uint_as_float(q1.x & 0xffff0000u);
        c0.z += e1 * __uint_as_float(q1.y << 16);
        c0.w += e1 * __uint_as_float(q1.y & 0xffff0000u);
        c1.x += e1 * __uint_as_float(q1.z << 16);
        c1.y += e1 * __uint_as_float(q1.z & 0xffff0000u);
        c1.z += e1 * __uint_as_float(q1.w << 16);
        c1.w += e1 * __uint_as_float(q1.w & 0xffff0000u);
        a0.x += e2 * __uint_as_float(q2.x << 16);
        a0.y += e2 * __uint_as_float(q2.x & 0xffff0000u);
        a0.z += e2 * __uint_as_float(q2.y << 16);
        a0.w += e2 * __uint_as_float(q2.y & 0xffff0000u);
        a1.x += e2 * __uint_as_float(q2.z << 16);
        a1.y += e2 * __uint_as_float(q2.z & 0xffff0000u);
        a1.z += e2 * __uint_as_float(q2.w << 16);
        a1.w += e2 * __uint_as_float(q2.w & 0xffff0000u);
        c0.x += e3 * __uint_as_float(q3.x << 16);
        c0.y += e3 * __uint_as_float(q3.x & 0xffff0000u);
        c0.z += e3 * __uint_as_float(q3.y << 16);
        c0.w += e3 * __uint_as_float(q3.y & 0xffff0000u);
        c1.x += e3 * __uint_as_float(q3.z << 16);
        c1.y += e3 * __uint_as_float(q3.z & 0xffff0000u);
        c1.z += e3 * __uint_as_float(q3.w << 16);
        c1.w += e3 * __uint_as_float(q3.w & 0xffff0000u);
    }
    a0.x += c0.x; a0.y += c0.y; a0.z += c0.z; a0.w += c0.w;
    a1.x += c1.x; a1.y += c1.y; a1.z += c1.z; a1.w += c1.w;

    float r = 1.f / (den + 1e-16f);
    float4 b0 = *reinterpret_cast<const float4*>(bias + l * 8);
    float4 b1 = *reinterpret_cast<const float4*>(bias + l * 8 + 4);
    float4 v0, v1;
    v0.x = a0.x * r + b0.x; v0.y = a0.y * r + b0.y;
    v0.z = a0.z * r + b0.z; v0.w = a0.w * r + b0.w;
    v1.x = a1.x * r + b1.x; v1.y = a1.y * r + b1.y;
    v1.z = a1.z * r + b1.z; v1.w = a1.w * r + b1.w;
    v0.x = (v0.x > 0.f) ? v0.x : expm1f(v0.x);
    v0.y = (v0.y > 0.f) ? v0.y : expm1f(v0.y);
    v0.z = (v0.z > 0.f) ? v0.z : expm1f(v0.z);
    v0.w = (v0.w > 0.f) ? v0.w : expm1f(v0.w);
    v1.x = (v1.x > 0.f) ? v1.x : expm1f(v1.x);
    v1.y = (v1.y > 0.f) ? v1.y : expm1f(v1.y);
    v1.z = (v1.z > 0.f) ? v1.z : expm1f(v1.z);
    v1.w = (v1.w > 0.f) ? v1.w : expm1f(v1.w);

    uint4 u;
    u.x = (unsigned)bf16_rne(v0.x) | ((unsigned)bf16_rne(v0.y) << 16);
    u.y = (unsigned)bf16_rne(v0.z) | ((unsigned)bf16_rne(v0.w) << 16);
    u.z = (unsigned)bf16_rne(v1.x) | ((unsigned)bf16_rne(v1.y) << 16);
    u.w = (unsigned)bf16_rne(v1.z) | ((unsigned)bf16_rne(v1.w) << 16);
    *reinterpret_cast<uint4*>(outbf + (size_t)d * 128 + l * 8) = u;
}

// ===== layer 2: single-pass softmax + split aggr + log_softmax ==============
__global__ __launch_bounds__(256) void gat40_k(
        const int* __restrict__ begA, const int* __restrict__ endA,
        const int* __restrict__ cols, const unsigned short* __restrict__ H32,
        const unsigned short* __restrict__ H8, const float* __restrict__ ssrc,
        const float* __restrict__ sdst, const float* __restrict__ b2,
        float* __restrict__ out, int n) {
    int d = (blockIdx.x * 256 + threadIdx.x) >> 4;
    if (d >= n) return;
    int l = threadIdx.x & 15;
    int beg = begA[d], end = endA[d];
    float sd = sdst[d];

    bool lo32 = (l < 8);
    int o32 = l * 4;
    int o8  = ((l >= 8 && l < 10) ? (l - 8) : 0) * 4;

    float4 acc = {0.f, 0.f, 0.f, 0.f};
    float4 acc2 = {0.f, 0.f, 0.f, 0.f};
    float den = 0.f;

    auto proc = [&](int i, float4& p) {
        int s = cols[i];
        float v = ssrc[s] + sd;
        v = (v >= 0.f) ? v : NEG_SLOPE * v;
        float a = __expf(v);
        den += a;
        const unsigned short* hp = lo32 ? (H32 + (size_t)s * 32 + o32)
                                        : (H8  + (size_t)s * 8  + o8);
        uint2 q = *reinterpret_cast<const uint2*>(hp);
        p.x += a * __uint_as_float(q.x << 16);
        p.y += a * __uint_as_float(q.x & 0xffff0000u);
        p.z += a * __uint_as_float(q.y << 16);
        p.w += a * __uint_as_float(q.y & 0xffff0000u);
    };
    int i = beg;
    int rem = (end - beg) & 3;
    if (rem & 1) { proc(i, acc); ++i; }
    if (rem & 2) { proc(i, acc); proc(i + 1, acc2); i += 2; }
    for (; i < end; i += 4) {
        int s0 = cols[i], s1 = cols[i + 1], s2 = cols[i + 2], s3 = cols[i + 3];
        float w0 = ssrc[s0] + sd, w1 = ssrc[s1] + sd;
        float w2 = ssrc[s2] + sd, w3 = ssrc[s3] + sd;
        const unsigned short* p0 = lo32 ? (H32 + (size_t)s0 * 32 + o32) : (H8 + (size_t)s0 * 8 + o8);
        const unsigned short* p1 = lo32 ? (H32 + (size_t)s1 * 32 + o32) : (H8 + (size_t)s1 * 8 + o8);
        const unsigned short* p2 = lo32 ? (H32 + (size_t)s2 * 32 + o32) : (H8 + (size_t)s2 * 8 + o8);
        const unsigned short* p3 = lo32 ? (H32 + (size_t)s3 * 32 + o32) : (H8 + (size_t)s3 * 8 + o8);
        uint2 q0 = *reinterpret_cast<const uint2*>(p0);
        uint2 q1 = *reinterpret_cast<const uint2*>(p1);
        uint2 q2 = *reinterpret_cast<const uint2*>(p2);
        uint2 q3 = *reinterpret_cast<const uint2*>(p3);
        w0 = (w0 >= 0.f) ? w0 : NEG_SLOPE * w0;
        w1 = (w1 >= 0.f) ? w1 : NEG_SLOPE * w1;
        w2 = (w2 >= 0.f) ? w2 : NEG_SLOPE * w2;
        w3 = (w3 >= 0.f) ? w3 : NEG_SLOPE * w3;
        float e0 = __expf(w0), e1 = __expf(w1);
        float e2 = __expf(w2), e3 = __expf(w3);
        den += e0 + e1 + e2 + e3;
        acc.x += e0 * __uint_as_float(q0.x << 16);
        acc.y += e0 * __uint_as_float(q0.x & 0xffff0000u);
        acc.z += e0 * __uint_as_float(q0.y << 16);
        acc.w += e0 * __uint_as_float(q0.y & 0xffff0000u);
        acc2.x += e1 * __uint_as_float(q1.x << 16);
        acc2.y += e1 * __uint_as_float(q1.x & 0xffff0000u);
        acc2.z += e1 * __uint_as_float(q1.y << 16);
        acc2.w += e1 * __uint_as_float(q1.y & 0xffff0000u);
        acc.x += e2 * __uint_as_float(q2.x << 16);
        acc.y += e2 * __uint_as_float(q2.x & 0xffff0000u);
        acc.z += e2 * __uint_as_float(q2.y << 16);
        acc.w += e2 * __uint_as_float(q2.y & 0xffff0000u);
        acc2.x += e3 * __uint_as_float(q3.x << 16);
        acc2.y += e3 * __uint_as_float(q3.x & 0xffff0000u);
        acc2.z += e3 * __uint_as_float(q3.y << 16);
        acc2.w += e3 * __uint_as_float(q3.y & 0xffff0000u);
    }
    acc.x += acc2.x; acc.y += acc2.y; acc.z += acc2.z; acc.w += acc2.w;

    float r = 1.f / (den + 1e-16f);
    float4 v4 = {0.f, 0.f, 0.f, 0.f};
    float mm = -1e30f;
    if (l < 10) {
        float4 b = *reinterpret_cast<const float4*>(b2 + l * 4);
        v4.x = acc.x * r + b.x; v4.y = acc.y * r + b.y;
        v4.z = acc.z * r + b.z; v4.w = acc.w * r + b.w;
        mm = fmaxf(fmaxf(v4.x, v4.y), fmaxf(v4.z, v4.w));
    }
    for (int off = 8; off > 0; off >>= 1) mm = fmaxf(mm, __shfl_xor(mm, off, 16));
    float ss = 0.f;
    if (l < 10)
        ss = __expf(v4.x - mm) + __expf(v4.y - mm) + __expf(v4.z - mm) + __expf(v4.w - mm);
    for (int off = 8; off > 0; off >>= 1) ss += __shfl_xor(ss, off, 16);
    float lse = mm + logf(ss);
    if (l < 10) {
        float4 o;
        o.x = v4.x - lse; o.y = v4.y - lse; o.z = v4.z - lse; o.w = v4.w - lse;
        *reinterpret_cast<float4*>(out + (size_t)d * 40 + l * 4) = o;
    }
}

static inline dim3 g1(long t) { return dim3((unsigned)((t + 255) / 256)); }

extern "C" void kernel_launch(void* const* d_in, const int* in_sizes, int n_in,
                              void* d_out, int out_size, void* d_ws, size_t ws_size,
                              hipStream_t stream) {
    const float* x      = (const float*)d_in[0];
    const int*   ei     = (const int*)d_in[1];
    const float* W0     = (const float*)d_in[2];
    const float* a_src0 = (const float*)d_in[3];
    const float* a_dst0 = (const float*)d_in[4];
    const float* b0     = (const float*)d_in[5];
    const float* W1     = (const float*)d_in[6];
    const float* a_src1 = (const float*)d_in[7];
    const float* a_dst1 = (const float*)d_in[8];
    const float* b1     = (const float*)d_in[9];
    const float* W2     = (const float*)d_in[10];
    const float* a_src2 = (const float*)d_in[11];
    const float* a_dst2 = (const float*)d_in[12];
    const float* b2     = (const float*)d_in[13];

    const int N    = in_sizes[0] / FIN;
    const int E    = in_sizes[1] / 2;
    const int Etot = E + N;
    const int NB   = (N + BKT - 1) / BKT;

    float* ws = (float*)d_ws;
    size_t o = 0;
    unsigned short* Hbf = (unsigned short*)(ws + o); o += (size_t)N * FIN / 2;
    unsigned short* Obf = (unsigned short*)(ws + o); o += (size_t)N * FIN / 2;
    unsigned short* H8  = (unsigned short*)(ws + o); o += (size_t)N * 4;
    float* ssrcA = ws + o; o += (size_t)N * HEADS;
    float* sdstA = ws + o; o += (size_t)N * HEADS;
    float* ssrcB = ws + o; o += (size_t)N * HEADS;
    float* sdstB = ws + o; o += (size_t)N * HEADS;
    int* gcur1  = (int*)(ws + o); o += NB_MAX;
    int* begA   = (int*)(ws + o); o += N;
    int* endA   = (int*)(ws + o); o += N;
    int* cols   = (int*)(ws + o); o += (size_t)NB_MAX * CAP;
    unsigned* pairs = (unsigned*)(ws + o); o += (size_t)NB_MAX * CAP;
    unsigned short* Bhi0 = (unsigned short*)(ws + o); o += 4 * 8 * 64 * 8 / 2;
    unsigned short* Blo0 = (unsigned short*)(ws + o); o += 4 * 8 * 64 * 8 / 2;
    unsigned short* Bhi1 = (unsigned short*)(ws + o); o += 4 * 8 * 64 * 8 / 2;
    unsigned short* Blo1 = (unsigned short*)(ws + o); o += 4 * 8 * 64 * 8 / 2;
    unsigned short* Bhi2 = (unsigned short*)(ws + o); o += 4 * 3 * 64 * 8 / 2;
    unsigned short* Blo2 = (unsigned short*)(ws + o); o += 4 * 3 * 64 * 8 / 2;
    unsigned short* Shi0 = (unsigned short*)(ws + o); o += 4 * 64 * 8 / 2;
    unsigned short* Slo0 = (unsigned short*)(ws + o); o += 4 * 64 * 8 / 2;
    unsigned short* Shi1 = (unsigned short*)(ws + o); o += 4 * 64 * 8 / 2;
    unsigned short* Slo1 = (unsigned short*)(ws + o); o += 4 * 64 * 8 / 2;
    unsigned short* Shi2 = (unsigned short*)(ws + o); o += 4 * 64 * 8 / 2;
    unsigned short* Slo2 = (unsigned short*)(ws + o); o += 4 * 64 * 8 / 2;

    const int gemmBlocks = (N + 127) / 128;
    const int grpBlocks  = (N * 16 + 255) / 256;
    const int eTiles     = (Etot + TILE_E - 1) / TILE_E;

    // ---------------- setup: pack + one-pass CSR ----------------------------
    packAll_k<<<g1(45056 + NB_MAX), 256, 0, stream>>>(
        W0, W1, W2, a_src0, a_dst0, a_src1, a_dst1, a_src2, a_dst2,
        Bhi0, Blo0, Bhi1, Blo1, Bhi2, Blo2,
        Shi0, Slo0, Shi1, Slo1, Shi2, Slo2, gcur1);
    placeA_k<<<eTiles, 256, 0, stream>>>(ei, E, Etot, NB, gcur1, pairs);
    buildcsr_k<<<NB, 256, 0, stream>>>(pairs, gcur1, begA, endA, cols, N);

    // ---------------- Layer 0 ----------------------------------------------
    gemm_fused_k<8, 4><<<gemmBlocks, 256, 0, stream>>>(x, Bhi0, Blo0, Shi0, Slo0, Hbf, ssrcA, sdstA, N, 128);
    gat128_k<<<grpBlocks, 256, 0, stream>>>(begA, endA, cols, Hbf, ssrcA, sdstA, b0, Obf, N);

    // ---------------- Layer 1 ----------------------------------------------
    gemm_bf16s_k<8, 4, false><<<gemmBlocks, 256, 0, stream>>>(Obf, Bhi1, Blo1, Shi1, Slo1, Hbf, nullptr, ssrcB, sdstB, N, 128);
    gat128_k<<<grpBlocks, 256, 0, stream>>>(begA, endA, cols, Hbf, ssrcB, sdstB, b1, Obf, N);

    // ---------------- Layer 2 (split H32/H8; fused log_softmax) -------------
    gemm_bf16s_k<3, 1, true><<<gemmBlocks, 256, 0, stream>>>(Obf, Bhi2, Blo2, Shi2, Slo2, Hbf, H8, ssrcA, sdstA, N, NCLS);
    gat40_k<<<grpBlocks, 256, 0, stream>>>(begA, endA, cols, Hbf, H8, ssrcA, sdstA, b2, (float*)d_out, N);
}